// Round 1
// 410.969 us; speedup vs baseline: 1.0317x; 1.0317x over previous
//
#include <hip/hip_runtime.h>
#include <math.h>

#define TPB 256
#define PMAX 128       // max partitions
#define PSH 10         // partition = dst >> 10 (1024 nodes/partition; n <= 131072)
#define PW  1024       // nodes per partition
#define CHUNK 8192     // edges per block in count/scatter

__device__ __forceinline__ float leaky02(float x) { return x > 0.f ? x : 0.2f * x; }
__device__ __forceinline__ float eluf(float x) { return x > 0.f ? x : (__expf(x) - 1.f); }

// ====================== CSR build (radix-style: count -> scan -> scatter -> finalize) ======================

// chunked per-block partition count; persists counts[b][p] for the scatter pass.
__global__ __launch_bounds__(256) void count_kernel(const int* __restrict__ dst, int E, int n,
                                                    int* __restrict__ counts) {
  __shared__ int lcnt[PMAX];
  int Etot = E + n;
  int c0 = blockIdx.x * CHUNK;
  if (c0 >= Etot) return;
  int c1 = min(c0 + CHUNK, Etot);
  for (int j = threadIdx.x; j < PMAX; j += TPB) lcnt[j] = 0;
  __syncthreads();
  for (int idx = c0 + threadIdx.x; idx < c1; idx += TPB) {
    int dd = (idx < E) ? dst[idx] : (idx - E);
    atomicAdd(&lcnt[dd >> PSH], 1);
  }
  __syncthreads();
  for (int j = threadIdx.x; j < PMAX; j += TPB)
    counts[blockIdx.x * PMAX + j] = lcnt[j];
}

// parallel partition scan: coalesced column-sum of counts[nbC][PMAX], then LDS scan.
__global__ __launch_bounds__(512) void pscan_kernel(const int* __restrict__ counts, int nbC,
                                                    int* __restrict__ pbase,
                                                    int* __restrict__ pcursor) {
  __shared__ int part[4][PMAX];
  __shared__ int ssum[PMAX];
  int t = threadIdx.x;
  int p = t & (PMAX - 1);
  int sub = t >> 7;
  int acc = 0;
#pragma unroll 4
  for (int b = sub; b < nbC; b += 4) acc += counts[b * PMAX + p];
  part[sub][p] = acc;
  __syncthreads();
  int own = 0;
  if (t < PMAX) {
    own = part[0][t] + part[1][t] + part[2][t] + part[3][t];
    ssum[t] = own;
  }
  __syncthreads();
  for (int off = 1; off < PMAX; off <<= 1) {
    int a = 0;
    if (t < PMAX && t >= off) a = ssum[t - off];
    __syncthreads();
    if (t < PMAX) ssum[t] += a;
    __syncthreads();
  }
  if (t < PMAX) {
    int incl = ssum[t];
    int excl = incl - own;
    pbase[t] = excl;
    pcursor[t] = excl;
    if (t == PMAX - 1) pbase[PMAX] = incl;
  }
}

// scatter using the persisted counts (no recount): 128 global atomics per block.
__global__ __launch_bounds__(256) void scatter_kernel(const int* __restrict__ src,
                                                      const int* __restrict__ dst,
                                                      int E, int n,
                                                      const int* __restrict__ counts,
                                                      int* __restrict__ pcursor,
                                                      unsigned* __restrict__ pstage) {
  __shared__ int lbase[PMAX];
  __shared__ int lcnt[PMAX];
  int Etot = E + n;
  int c0 = blockIdx.x * CHUNK;
  if (c0 >= Etot) return;
  int c1 = min(c0 + CHUNK, Etot);
  for (int j = threadIdx.x; j < PMAX; j += TPB) {
    int c = counts[blockIdx.x * PMAX + j];
    lbase[j] = atomicAdd(&pcursor[j], c);
    lcnt[j] = 0;
  }
  __syncthreads();
  for (int idx = c0 + threadIdx.x; idx < c1; idx += TPB) {
    int ss, dd;
    if (idx < E) { ss = src[idx]; dd = dst[idx]; }
    else         { ss = dd = idx - E; }
    int p = dd >> PSH;
    int pos = lbase[p] + atomicAdd(&lcnt[p], 1);
    pstage[pos] = ((unsigned)ss << PSH) | (unsigned)(dd & (PW - 1));
  }
}

// One 1024-thread block per partition; PW=1024 -> one hist entry per thread.
// shfl-based scan: 4 barriers instead of 21.
__global__ __launch_bounds__(1024) void build_csr_kernel(const unsigned* __restrict__ pstage,
                                                         const int* __restrict__ pbase,
                                                         int nvtx,
                                                         int* __restrict__ rowptr,
                                                         int* __restrict__ csr_src) {
  __shared__ int lhist[PW];
  __shared__ int lcur[PW];
  int t = threadIdx.x;
  int lane = t & 63;
  int wid = t >> 6;
  int p = blockIdx.x;
  int base = pbase[p];
  int end = pbase[p + 1];
  int nodebase = p << PSH;
  lhist[t] = 0;
  __syncthreads();
  for (int i = base + t; i < end; i += 1024)
    atomicAdd(&lhist[pstage[i] & (PW - 1)], 1);
  __syncthreads();
  int v = lhist[t];
  int x = v;
#pragma unroll
  for (int off = 1; off < 64; off <<= 1) {
    int u = __shfl_up(x, off);
    if (lane >= off) x += u;
  }
  if (lane == 63) lcur[wid] = x;       // wave sums in lcur[0..15]
  __syncthreads();
  if (t < 16) {
    int wsum = lcur[t];
    int y = wsum;
#pragma unroll
    for (int off = 1; off < 16; off <<= 1) {
      int u = __shfl_up(y, off);
      if (t >= off) y += u;
    }
    lcur[t] = y - wsum;                // exclusive wave offsets
  }
  __syncthreads();
  int acc = base + x + lcur[wid] - v;  // exclusive start position of node t
  __syncthreads();
  lcur[t] = acc;
  int node = nodebase + t;
  if (node < nvtx) rowptr[node] = acc;
  __syncthreads();
  for (int i = base + t; i < end; i += 1024) {
    unsigned w = pstage[i];
    int pos = atomicAdd(&lcur[w & (PW - 1)], 1);
    csr_src[pos] = (int)(w >> PSH);
  }
  if (p == (int)gridDim.x - 1 && t == 0) rowptr[nvtx] = end;
}

// ====================== node transform (h = x@W, attn logits) ======================

template<int IN, int OUT, int H>
__global__ void transform_kernel(const float* __restrict__ x, const float* __restrict__ W,
                                 const float* __restrict__ a_src, const float* __restrict__ a_dst,
                                 float* __restrict__ h, float* __restrict__ asrc,
                                 float* __restrict__ adst, int n) {
  __shared__ float sW[IN * OUT];
  __shared__ float sa[2 * OUT];
  for (int i = threadIdx.x; i < IN * OUT; i += blockDim.x) sW[i] = W[i];
  if (threadIdx.x < OUT) {
    sa[threadIdx.x] = a_src[threadIdx.x];
    sa[OUT + threadIdx.x] = a_dst[threadIdx.x];
  }
  __syncthreads();
  int i = blockIdx.x * blockDim.x + threadIdx.x;
  if (i >= n) return;
  float xv[IN];
#pragma unroll
  for (int k = 0; k < IN; k++) xv[k] = x[(size_t)i * IN + k];
  float hv[OUT];
#pragma unroll
  for (int j = 0; j < OUT; j++) {
    float acc = 0.f;
#pragma unroll
    for (int k = 0; k < IN; k++) acc += xv[k] * sW[k * OUT + j];
    hv[j] = acc;
    h[(size_t)i * OUT + j] = acc;
  }
#pragma unroll
  for (int hh = 0; hh < H; hh++) {
    float as = 0.f, ad = 0.f;
#pragma unroll
    for (int c = 0; c < 16; c++) {
      as += hv[hh * 16 + c] * sa[hh * 16 + c];
      ad += hv[hh * 16 + c] * sa[OUT + hh * 16 + c];
    }
    asrc[i * H + hh] = as;
    adst[i * H + hh] = ad;
  }
}

// ====================== per-node GAT aggregation (1 wave / dst node) ======================
// Packed (sidx<<3, w0, sidx<<3, w1) float4 LDS entry: contiguous bank access
// (conflict-free), single ds_write_b128, pre-shifted index in the hot gather loop.

__global__ __launch_bounds__(256) void node_gat12(
    const int* __restrict__ rowptr,
    const int* __restrict__ csr_src,
    const float* __restrict__ asrc,  // [n*2]
    const float* __restrict__ adst,  // [n*2]
    const float* __restrict__ hfeat, // [n*32]
    const float* __restrict__ bias,  // [32]
    float* __restrict__ outb,        // [n*32]
    int n) {
  __shared__ float4 s_e[4][64];    // (sidx<<3, w0, sidx<<3, w1)
  int wid = threadIdx.x >> 6;
  int lane = threadIdx.x & 63;
  int i = (blockIdx.x * blockDim.x + threadIdx.x) >> 6;
  if (i >= n) return;
  int start = rowptr[i];
  int d = rowptr[i + 1] - start;
  float ad0 = adst[i * 2 + 0];
  float ad1 = adst[i * 2 + 1];
  const float4* hf4 = (const float4*)hfeat;
  int g = lane >> 3;   // edge group 0..7
  int q = lane & 7;    // float4 channel slot (q<4: head0, q>=4: head1)
  const float2* sp = (const float2*)(&s_e[wid][0]) + (q >> 2);  // head-selected base, hoisted
  float4 acc = make_float4(0.f, 0.f, 0.f, 0.f);
  float sl0 = 0.f, sl1 = 0.f;

  if (d <= 64) {
    int sidx8 = 0;
    float e0 = -3.4e38f, e1 = -3.4e38f;
    if (lane < d) {
      int sidx = csr_src[start + lane];
      sidx8 = sidx << 3;
      float2 av = ((const float2*)asrc)[sidx];
      e0 = leaky02(av.x + ad0);
      e1 = leaky02(av.y + ad1);
    }
    float m0 = e0, m1 = e1;
#pragma unroll
    for (int off = 32; off >= 1; off >>= 1) {
      m0 = fmaxf(m0, __shfl_xor(m0, off));
      m1 = fmaxf(m1, __shfl_xor(m1, off));
    }
    float w0 = 0.f, w1 = 0.f;
    if (lane < d) { w0 = __expf(e0 - m0); w1 = __expf(e1 - m1); }
    sl0 = w0; sl1 = w1;
    s_e[wid][lane] = make_float4(__int_as_float(sidx8), w0, __int_as_float(sidx8), w1);
    // same-wave LDS write->read ordering (R4-verified)
    for (int jj = g; jj < d; jj += 8) {
      float2 pw = sp[2 * jj];
      int sb8 = __float_as_int(pw.x);
      float w = pw.y;
      float4 hv = hf4[sb8 + q];
      acc.x += w * hv.x; acc.y += w * hv.y; acc.z += w * hv.z; acc.w += w * hv.w;
    }
  } else {
    float m0 = -3.4e38f, m1 = -3.4e38f;
    for (int k = lane; k < d; k += 64) {
      int sidx = csr_src[start + k];
      float2 av = ((const float2*)asrc)[sidx];
      m0 = fmaxf(m0, leaky02(av.x + ad0));
      m1 = fmaxf(m1, leaky02(av.y + ad1));
    }
#pragma unroll
    for (int off = 32; off >= 1; off >>= 1) {
      m0 = fmaxf(m0, __shfl_xor(m0, off));
      m1 = fmaxf(m1, __shfl_xor(m1, off));
    }
    for (int base = 0; base < d; base += 64) {
      int k = base + lane;
      int sidx8 = 0;
      float w0 = 0.f, w1 = 0.f;
      if (k < d) {
        int sidx = csr_src[start + k];
        sidx8 = sidx << 3;
        float2 av = ((const float2*)asrc)[sidx];
        w0 = __expf(leaky02(av.x + ad0) - m0);
        w1 = __expf(leaky02(av.y + ad1) - m1);
        sl0 += w0; sl1 += w1;
      }
      s_e[wid][lane] = make_float4(__int_as_float(sidx8), w0, __int_as_float(sidx8), w1);
      int cnt = min(64, d - base);
      for (int jj = g; jj < cnt; jj += 8) {
        float2 pw = sp[2 * jj];
        int sb8 = __float_as_int(pw.x);
        float w = pw.y;
        float4 hv = hf4[sb8 + q];
        acc.x += w * hv.x; acc.y += w * hv.y; acc.z += w * hv.z; acc.w += w * hv.w;
      }
    }
  }

#pragma unroll
  for (int off = 32; off >= 1; off >>= 1) {
    sl0 += __shfl_xor(sl0, off);
    sl1 += __shfl_xor(sl1, off);
  }
#pragma unroll
  for (int off = 8; off <= 32; off <<= 1) {
    acc.x += __shfl_xor(acc.x, off);
    acc.y += __shfl_xor(acc.y, off);
    acc.z += __shfl_xor(acc.z, off);
    acc.w += __shfl_xor(acc.w, off);
  }
  if (lane < 8) {
    float inv = 1.f / (((lane >= 4) ? sl1 : sl0) + 1e-16f);
    float4 bv = ((const float4*)bias)[lane];
    float4 o;
    o.x = eluf(acc.x * inv + bv.x);
    o.y = eluf(acc.y * inv + bv.y);
    o.z = eluf(acc.z * inv + bv.z);
    o.w = eluf(acc.w * inv + bv.w);
    ((float4*)outb)[(size_t)i * 8 + lane] = o;
  }
}

__global__ __launch_bounds__(256) void node_gat3(
    const int* __restrict__ rowptr,
    const int* __restrict__ csr_src,
    const float* __restrict__ asrc,  // [n]
    const float* __restrict__ adst,  // [n]
    const float* __restrict__ hfeat, // [n*16]
    const float* __restrict__ b3,    // [16]
    const float* __restrict__ Wout,  // [16]
    const float* __restrict__ bout,  // [1]
    float* __restrict__ out,         // [n] sigmoid ++ [n*16] embeddings
    int n) {
  __shared__ float2 s_hw[4][64];   // (sidx<<2, w)
  int wid = threadIdx.x >> 6;
  int lane = threadIdx.x & 63;
  int i = (blockIdx.x * blockDim.x + threadIdx.x) >> 6;
  if (i >= n) return;
  int start = rowptr[i];
  int d = rowptr[i + 1] - start;
  float ad0 = adst[i];
  const float4* hf4 = (const float4*)hfeat;
  int g = lane >> 2;   // edge group 0..15
  int q = lane & 3;    // float4 channel slot
  const float2* sp = s_hw[wid];
  float4 acc = make_float4(0.f, 0.f, 0.f, 0.f);
  float sl = 0.f;

  if (d <= 64) {
    int sidx4 = 0;
    float e0 = -3.4e38f;
    if (lane < d) {
      int sidx = csr_src[start + lane];
      sidx4 = sidx << 2;
      e0 = leaky02(asrc[sidx] + ad0);
    }
    float m0 = e0;
#pragma unroll
    for (int off = 32; off >= 1; off >>= 1) m0 = fmaxf(m0, __shfl_xor(m0, off));
    float w0 = (lane < d) ? __expf(e0 - m0) : 0.f;
    sl = w0;
    s_hw[wid][lane] = make_float2(__int_as_float(sidx4), w0);
    for (int jj = g; jj < d; jj += 16) {
      float2 pw = sp[jj];
      int sb4 = __float_as_int(pw.x);
      float w = pw.y;
      float4 hv = hf4[sb4 + q];
      acc.x += w * hv.x; acc.y += w * hv.y; acc.z += w * hv.z; acc.w += w * hv.w;
    }
  } else {
    float m0 = -3.4e38f;
    for (int k = lane; k < d; k += 64) {
      int sidx = csr_src[start + k];
      m0 = fmaxf(m0, leaky02(asrc[sidx] + ad0));
    }
#pragma unroll
    for (int off = 32; off >= 1; off >>= 1) m0 = fmaxf(m0, __shfl_xor(m0, off));
    for (int base = 0; base < d; base += 64) {
      int k = base + lane;
      int sidx4 = 0;
      float w0 = 0.f;
      if (k < d) {
        int sidx = csr_src[start + k];
        sidx4 = sidx << 2;
        w0 = __expf(leaky02(asrc[sidx] + ad0) - m0);
        sl += w0;
      }
      s_hw[wid][lane] = make_float2(__int_as_float(sidx4), w0);
      int cnt = min(64, d - base);
      for (int jj = g; jj < cnt; jj += 16) {
        float2 pw = sp[jj];
        int sb4 = __float_as_int(pw.x);
        float w = pw.y;
        float4 hv = hf4[sb4 + q];
        acc.x += w * hv.x; acc.y += w * hv.y; acc.z += w * hv.z; acc.w += w * hv.w;
      }
    }
  }

#pragma unroll
  for (int off = 32; off >= 1; off >>= 1) sl += __shfl_xor(sl, off);
#pragma unroll
  for (int off = 4; off <= 32; off <<= 1) {
    acc.x += __shfl_xor(acc.x, off);
    acc.y += __shfl_xor(acc.y, off);
    acc.z += __shfl_xor(acc.z, off);
    acc.w += __shfl_xor(acc.w, off);
  }
  float z = 0.f;
  if (lane < 4) {
    float inv = 1.f / (sl + 1e-16f);
    float4 bv = ((const float4*)b3)[lane];
    float4 wv = ((const float4*)Wout)[lane];
    float4 o;
    o.x = eluf(acc.x * inv + bv.x);
    o.y = eluf(acc.y * inv + bv.y);
    o.z = eluf(acc.z * inv + bv.z);
    o.w = eluf(acc.w * inv + bv.w);
    ((float4*)(out + n))[(size_t)i * 4 + lane] = o;
    z = o.x * wv.x + o.y * wv.y + o.z * wv.z + o.w * wv.w;
  }
  z += __shfl_xor(z, 1);
  z += __shfl_xor(z, 2);
  if (lane == 0) out[i] = 1.f / (1.f + __expf(-(z + bout[0])));
}

// ====================== launch ======================

extern "C" void kernel_launch(void* const* d_in, const int* in_sizes, int n_in,
                              void* d_out, int out_size, void* d_ws, size_t ws_size,
                              hipStream_t stream) {
  const float* x    = (const float*)d_in[0];
  const int*   ei   = (const int*)d_in[1];
  const float* W1   = (const float*)d_in[2];
  const float* as1  = (const float*)d_in[3];
  const float* ad1  = (const float*)d_in[4];
  const float* b1   = (const float*)d_in[5];
  const float* W2   = (const float*)d_in[6];
  const float* as2  = (const float*)d_in[7];
  const float* ad2  = (const float*)d_in[8];
  const float* b2   = (const float*)d_in[9];
  const float* W3   = (const float*)d_in[10];
  const float* as3  = (const float*)d_in[11];
  const float* ad3  = (const float*)d_in[12];
  const float* b3   = (const float*)d_in[13];
  const float* Wout = (const float*)d_in[14];
  const float* bout = (const float*)d_in[15];
  float* out = (float*)d_out;

  const int n = in_sizes[0] / 3;
  const int E = in_sizes[1] / 2;
  const int Etot = E + n;
  const int* src = ei;
  const int* dst = ei + E;
  const int nbC = (Etot + CHUNK - 1) / CHUNK;
  const int NP = ((n - 1) >> PSH) + 1;   // n=100000 -> 98 partitions

  float* ws = (float*)d_ws;
  float* bufH = ws;                               // n*32
  float* bufX = bufH + (size_t)n * 32;            // n*32
  float* asrc = bufX + (size_t)n * 32;            // n*2
  float* adst = asrc + (size_t)n * 2;             // n*2
  int* rowptr  = (int*)(adst + (size_t)n * 2);    // n+1
  int* pbase   = rowptr + n + 1;                  // PMAX+1
  int* pcursor = pbase + PMAX + 1;                // PMAX
  int* pcount  = pcursor + PMAX;                  // PMAX (unused, layout kept)
  int* csr_src = pcount + PMAX;                   // Etot
  int* counts  = csr_src + Etot;                  // nbC*PMAX (~207 KB)
  unsigned* pstage = (unsigned*)ws;               // Etot (aliases bufH..; dead before transforms)

  const int nbN = (n + TPB - 1) / TPB;
  const int nbW = (n + 3) / 4;

  // ---- CSR build ----
  count_kernel<<<nbC, TPB, 0, stream>>>(dst, E, n, counts);
  pscan_kernel<<<1, 512, 0, stream>>>(counts, nbC, pbase, pcursor);
  scatter_kernel<<<nbC, TPB, 0, stream>>>(src, dst, E, n, counts, pcursor, pstage);
  build_csr_kernel<<<NP, 1024, 0, stream>>>(pstage, pbase, n, rowptr, csr_src);

  // ---- layer 1: in=3, out=32, H=2 ----
  transform_kernel<3, 32, 2><<<nbN, TPB, 0, stream>>>(x, W1, as1, ad1, bufH, asrc, adst, n);
  node_gat12<<<nbW, TPB, 0, stream>>>(rowptr, csr_src, asrc, adst, bufH, b1, bufX, n);

  // ---- layer 2: in=32, out=32, H=2 ----
  transform_kernel<32, 32, 2><<<nbN, TPB, 0, stream>>>(bufX, W2, as2, ad2, bufH, asrc, adst, n);
  node_gat12<<<nbW, TPB, 0, stream>>>(rowptr, csr_src, asrc, adst, bufH, b2, bufX, n);

  // ---- layer 3: in=32, out=16, H=1 ----
  transform_kernel<32, 16, 1><<<nbN, TPB, 0, stream>>>(bufX, W3, as3, ad3, bufH, asrc, adst, n);
  node_gat3<<<nbW, TPB, 0, stream>>>(rowptr, csr_src, asrc, adst, bufH, b3, Wout, bout, out, n);
}

// Round 2
// 401.608 us; speedup vs baseline: 1.0557x; 1.0233x over previous
//
#include <hip/hip_runtime.h>
#include <math.h>

#define TPB 256
#define PMAX 128       // max partitions
#define PSH 10         // partition = dst >> 10 (1024 nodes/partition; n <= 131072)
#define PW  1024       // nodes per partition
#define CHUNK 8192     // edges per block in count/scatter

__device__ __forceinline__ float leaky02(float x) { return x > 0.f ? x : 0.2f * x; }
__device__ __forceinline__ float eluf(float x) { return x > 0.f ? x : (__expf(x) - 1.f); }

// ====================== CSR build (radix-style: count -> scan -> scatter -> finalize) ======================

__global__ __launch_bounds__(256) void count_kernel(const int* __restrict__ dst, int E, int n,
                                                    int* __restrict__ counts) {
  __shared__ int lcnt[PMAX];
  int Etot = E + n;
  int c0 = blockIdx.x * CHUNK;
  if (c0 >= Etot) return;
  int c1 = min(c0 + CHUNK, Etot);
  for (int j = threadIdx.x; j < PMAX; j += TPB) lcnt[j] = 0;
  __syncthreads();
  for (int idx = c0 + threadIdx.x; idx < c1; idx += TPB) {
    int dd = (idx < E) ? dst[idx] : (idx - E);
    atomicAdd(&lcnt[dd >> PSH], 1);
  }
  __syncthreads();
  for (int j = threadIdx.x; j < PMAX; j += TPB)
    counts[blockIdx.x * PMAX + j] = lcnt[j];
}

// parallel partition scan: coalesced column-sum of counts[nbC][PMAX], then LDS scan.
__global__ __launch_bounds__(512) void pscan_kernel(const int* __restrict__ counts, int nbC,
                                                    int* __restrict__ pbase,
                                                    int* __restrict__ pcursor) {
  __shared__ int part[4][PMAX];
  __shared__ int ssum[PMAX];
  int t = threadIdx.x;
  int p = t & (PMAX - 1);
  int sub = t >> 7;
  int acc = 0;
#pragma unroll 4
  for (int b = sub; b < nbC; b += 4) acc += counts[b * PMAX + p];
  part[sub][p] = acc;
  __syncthreads();
  int own = 0;
  if (t < PMAX) {
    own = part[0][t] + part[1][t] + part[2][t] + part[3][t];
    ssum[t] = own;
  }
  __syncthreads();
  for (int off = 1; off < PMAX; off <<= 1) {
    int a = 0;
    if (t < PMAX && t >= off) a = ssum[t - off];
    __syncthreads();
    if (t < PMAX) ssum[t] += a;
    __syncthreads();
  }
  if (t < PMAX) {
    int incl = ssum[t];
    int excl = incl - own;
    pbase[t] = excl;
    pcursor[t] = excl;
    if (t == PMAX - 1) pbase[PMAX] = incl;
  }
}

__global__ __launch_bounds__(256) void scatter_kernel(const int* __restrict__ src,
                                                      const int* __restrict__ dst,
                                                      int E, int n,
                                                      const int* __restrict__ counts,
                                                      int* __restrict__ pcursor,
                                                      unsigned* __restrict__ pstage) {
  __shared__ int lbase[PMAX];
  __shared__ int lcnt[PMAX];
  int Etot = E + n;
  int c0 = blockIdx.x * CHUNK;
  if (c0 >= Etot) return;
  int c1 = min(c0 + CHUNK, Etot);
  for (int j = threadIdx.x; j < PMAX; j += TPB) {
    int c = counts[blockIdx.x * PMAX + j];
    lbase[j] = atomicAdd(&pcursor[j], c);
    lcnt[j] = 0;
  }
  __syncthreads();
  for (int idx = c0 + threadIdx.x; idx < c1; idx += TPB) {
    int ss, dd;
    if (idx < E) { ss = src[idx]; dd = dst[idx]; }
    else         { ss = dd = idx - E; }
    int p = dd >> PSH;
    int pos = lbase[p] + atomicAdd(&lcnt[p], 1);
    pstage[pos] = ((unsigned)ss << PSH) | (unsigned)(dd & (PW - 1));
  }
}

// One 1024-thread block per partition; shfl-based scan (4 barriers).
__global__ __launch_bounds__(1024) void build_csr_kernel(const unsigned* __restrict__ pstage,
                                                         const int* __restrict__ pbase,
                                                         int nvtx,
                                                         int* __restrict__ rowptr,
                                                         int* __restrict__ csr_src) {
  __shared__ int lhist[PW];
  __shared__ int lcur[PW];
  int t = threadIdx.x;
  int lane = t & 63;
  int wid = t >> 6;
  int p = blockIdx.x;
  int base = pbase[p];
  int end = pbase[p + 1];
  int nodebase = p << PSH;
  lhist[t] = 0;
  __syncthreads();
  for (int i = base + t; i < end; i += 1024)
    atomicAdd(&lhist[pstage[i] & (PW - 1)], 1);
  __syncthreads();
  int v = lhist[t];
  int x = v;
#pragma unroll
  for (int off = 1; off < 64; off <<= 1) {
    int u = __shfl_up(x, off);
    if (lane >= off) x += u;
  }
  if (lane == 63) lcur[wid] = x;       // wave sums in lcur[0..15]
  __syncthreads();
  if (t < 16) {
    int wsum = lcur[t];
    int y = wsum;
#pragma unroll
    for (int off = 1; off < 16; off <<= 1) {
      int u = __shfl_up(y, off);
      if (t >= off) y += u;
    }
    lcur[t] = y - wsum;                // exclusive wave offsets
  }
  __syncthreads();
  int acc = base + x + lcur[wid] - v;  // exclusive start position of node t
  __syncthreads();
  lcur[t] = acc;
  int node = nodebase + t;
  if (node < nvtx) rowptr[node] = acc;
  __syncthreads();
  for (int i = base + t; i < end; i += 1024) {
    unsigned w = pstage[i];
    int pos = atomicAdd(&lcur[w & (PW - 1)], 1);
    csr_src[pos] = (int)(w >> PSH);
  }
  if (p == (int)gridDim.x - 1 && t == 0) rowptr[nvtx] = end;
}

// ====================== node transform (h = x@W, attn logits) ======================

template<int IN, int OUT, int H>
__global__ void transform_kernel(const float* __restrict__ x, const float* __restrict__ W,
                                 const float* __restrict__ a_src, const float* __restrict__ a_dst,
                                 float* __restrict__ h, float* __restrict__ asrc,
                                 float* __restrict__ adst, int n) {
  __shared__ float sW[IN * OUT];
  __shared__ float sa[2 * OUT];
  for (int i = threadIdx.x; i < IN * OUT; i += blockDim.x) sW[i] = W[i];
  if (threadIdx.x < OUT) {
    sa[threadIdx.x] = a_src[threadIdx.x];
    sa[OUT + threadIdx.x] = a_dst[threadIdx.x];
  }
  __syncthreads();
  int i = blockIdx.x * blockDim.x + threadIdx.x;
  if (i >= n) return;
  float xv[IN];
#pragma unroll
  for (int k = 0; k < IN; k++) xv[k] = x[(size_t)i * IN + k];
  float hv[OUT];
#pragma unroll
  for (int j = 0; j < OUT; j++) {
    float acc = 0.f;
#pragma unroll
    for (int k = 0; k < IN; k++) acc += xv[k] * sW[k * OUT + j];
    hv[j] = acc;
    h[(size_t)i * OUT + j] = acc;
  }
#pragma unroll
  for (int hh = 0; hh < H; hh++) {
    float as = 0.f, ad = 0.f;
#pragma unroll
    for (int c = 0; c < 16; c++) {
      as += hv[hh * 16 + c] * sa[hh * 16 + c];
      ad += hv[hh * 16 + c] * sa[OUT + hh * 16 + c];
    }
    asrc[i * H + hh] = as;
    adst[i * H + hh] = ad;
  }
}

// ====================== per-node GAT aggregation (1 wave / dst node) ======================
// Unrolled gather: 4 independent global_load_dwordx4 in flight per lane (MLP x4).

__device__ __forceinline__ void gather12(const float2* __restrict__ sp,
                                         const float4* __restrict__ hf4,
                                         int q, int g, int cnt, float4& acc) {
  int jj = g;
  for (; jj + 24 < cnt; jj += 32) {
    float2 p0 = sp[2 * jj];
    float2 p1 = sp[2 * (jj + 8)];
    float2 p2 = sp[2 * (jj + 16)];
    float2 p3 = sp[2 * (jj + 24)];
    float4 h0 = hf4[__float_as_int(p0.x) + q];
    float4 h1 = hf4[__float_as_int(p1.x) + q];
    float4 h2 = hf4[__float_as_int(p2.x) + q];
    float4 h3 = hf4[__float_as_int(p3.x) + q];
    acc.x += p0.y * h0.x; acc.y += p0.y * h0.y; acc.z += p0.y * h0.z; acc.w += p0.y * h0.w;
    acc.x += p1.y * h1.x; acc.y += p1.y * h1.y; acc.z += p1.y * h1.z; acc.w += p1.y * h1.w;
    acc.x += p2.y * h2.x; acc.y += p2.y * h2.y; acc.z += p2.y * h2.z; acc.w += p2.y * h2.w;
    acc.x += p3.y * h3.x; acc.y += p3.y * h3.y; acc.z += p3.y * h3.z; acc.w += p3.y * h3.w;
  }
  for (; jj + 8 < cnt; jj += 16) {
    float2 p0 = sp[2 * jj];
    float2 p1 = sp[2 * (jj + 8)];
    float4 h0 = hf4[__float_as_int(p0.x) + q];
    float4 h1 = hf4[__float_as_int(p1.x) + q];
    acc.x += p0.y * h0.x; acc.y += p0.y * h0.y; acc.z += p0.y * h0.z; acc.w += p0.y * h0.w;
    acc.x += p1.y * h1.x; acc.y += p1.y * h1.y; acc.z += p1.y * h1.z; acc.w += p1.y * h1.w;
  }
  if (jj < cnt) {
    float2 pw = sp[2 * jj];
    float4 hv = hf4[__float_as_int(pw.x) + q];
    acc.x += pw.y * hv.x; acc.y += pw.y * hv.y; acc.z += pw.y * hv.z; acc.w += pw.y * hv.w;
  }
}

__global__ __launch_bounds__(256) void node_gat12(
    const int* __restrict__ rowptr,
    const int* __restrict__ csr_src,
    const float* __restrict__ asrc,  // [n*2]
    const float* __restrict__ adst,  // [n*2]
    const float* __restrict__ hfeat, // [n*32]
    const float* __restrict__ bias,  // [32]
    float* __restrict__ outb,        // [n*32]
    int n) {
  __shared__ float4 s_e[4][64];    // (sidx<<3, w0, sidx<<3, w1)
  int wid = threadIdx.x >> 6;
  int lane = threadIdx.x & 63;
  int i = (blockIdx.x * blockDim.x + threadIdx.x) >> 6;
  if (i >= n) return;
  int start = rowptr[i];
  int d = rowptr[i + 1] - start;
  float ad0 = adst[i * 2 + 0];
  float ad1 = adst[i * 2 + 1];
  const float4* hf4 = (const float4*)hfeat;
  int g = lane >> 3;   // edge group 0..7
  int q = lane & 7;    // float4 channel slot (q<4: head0, q>=4: head1)
  const float2* sp = (const float2*)(&s_e[wid][0]) + (q >> 2);  // head-selected base
  float4 acc = make_float4(0.f, 0.f, 0.f, 0.f);
  float sl0 = 0.f, sl1 = 0.f;

  if (d <= 64) {
    int sidx8 = 0;
    float e0 = -3.4e38f, e1 = -3.4e38f;
    if (lane < d) {
      int sidx = csr_src[start + lane];
      sidx8 = sidx << 3;
      float2 av = ((const float2*)asrc)[sidx];
      e0 = leaky02(av.x + ad0);
      e1 = leaky02(av.y + ad1);
    }
    float m0 = e0, m1 = e1;
#pragma unroll
    for (int off = 32; off >= 1; off >>= 1) {
      m0 = fmaxf(m0, __shfl_xor(m0, off));
      m1 = fmaxf(m1, __shfl_xor(m1, off));
    }
    float w0 = 0.f, w1 = 0.f;
    if (lane < d) { w0 = __expf(e0 - m0); w1 = __expf(e1 - m1); }
    sl0 = w0; sl1 = w1;
    s_e[wid][lane] = make_float4(__int_as_float(sidx8), w0, __int_as_float(sidx8), w1);
    // same-wave LDS write->read ordering (R4-verified)
    gather12(sp, hf4, q, g, d, acc);
  } else {
    float m0 = -3.4e38f, m1 = -3.4e38f;
    for (int k = lane; k < d; k += 64) {
      int sidx = csr_src[start + k];
      float2 av = ((const float2*)asrc)[sidx];
      m0 = fmaxf(m0, leaky02(av.x + ad0));
      m1 = fmaxf(m1, leaky02(av.y + ad1));
    }
#pragma unroll
    for (int off = 32; off >= 1; off >>= 1) {
      m0 = fmaxf(m0, __shfl_xor(m0, off));
      m1 = fmaxf(m1, __shfl_xor(m1, off));
    }
    for (int base = 0; base < d; base += 64) {
      int k = base + lane;
      int sidx8 = 0;
      float w0 = 0.f, w1 = 0.f;
      if (k < d) {
        int sidx = csr_src[start + k];
        sidx8 = sidx << 3;
        float2 av = ((const float2*)asrc)[sidx];
        w0 = __expf(leaky02(av.x + ad0) - m0);
        w1 = __expf(leaky02(av.y + ad1) - m1);
        sl0 += w0; sl1 += w1;
      }
      s_e[wid][lane] = make_float4(__int_as_float(sidx8), w0, __int_as_float(sidx8), w1);
      int cnt = min(64, d - base);
      gather12(sp, hf4, q, g, cnt, acc);
    }
  }

#pragma unroll
  for (int off = 32; off >= 1; off >>= 1) {
    sl0 += __shfl_xor(sl0, off);
    sl1 += __shfl_xor(sl1, off);
  }
#pragma unroll
  for (int off = 8; off <= 32; off <<= 1) {
    acc.x += __shfl_xor(acc.x, off);
    acc.y += __shfl_xor(acc.y, off);
    acc.z += __shfl_xor(acc.z, off);
    acc.w += __shfl_xor(acc.w, off);
  }
  if (lane < 8) {
    float inv = 1.f / (((lane >= 4) ? sl1 : sl0) + 1e-16f);
    float4 bv = ((const float4*)bias)[lane];
    float4 o;
    o.x = eluf(acc.x * inv + bv.x);
    o.y = eluf(acc.y * inv + bv.y);
    o.z = eluf(acc.z * inv + bv.z);
    o.w = eluf(acc.w * inv + bv.w);
    ((float4*)outb)[(size_t)i * 8 + lane] = o;
  }
}

__device__ __forceinline__ void gather3(const float2* __restrict__ sp,
                                        const float4* __restrict__ hf4,
                                        int q, int g, int cnt, float4& acc) {
  int jj = g;
  for (; jj + 16 < cnt; jj += 32) {
    float2 p0 = sp[jj];
    float2 p1 = sp[jj + 16];
    float4 h0 = hf4[__float_as_int(p0.x) + q];
    float4 h1 = hf4[__float_as_int(p1.x) + q];
    acc.x += p0.y * h0.x; acc.y += p0.y * h0.y; acc.z += p0.y * h0.z; acc.w += p0.y * h0.w;
    acc.x += p1.y * h1.x; acc.y += p1.y * h1.y; acc.z += p1.y * h1.z; acc.w += p1.y * h1.w;
  }
  if (jj < cnt) {
    float2 pw = sp[jj];
    float4 hv = hf4[__float_as_int(pw.x) + q];
    acc.x += pw.y * hv.x; acc.y += pw.y * hv.y; acc.z += pw.y * hv.z; acc.w += pw.y * hv.w;
  }
}

__global__ __launch_bounds__(256) void node_gat3(
    const int* __restrict__ rowptr,
    const int* __restrict__ csr_src,
    const float* __restrict__ asrc,  // [n]
    const float* __restrict__ adst,  // [n]
    const float* __restrict__ hfeat, // [n*16]
    const float* __restrict__ b3,    // [16]
    const float* __restrict__ Wout,  // [16]
    const float* __restrict__ bout,  // [1]
    float* __restrict__ out,         // [n] sigmoid ++ [n*16] embeddings
    int n) {
  __shared__ float2 s_hw[4][64];   // (sidx<<2, w)
  int wid = threadIdx.x >> 6;
  int lane = threadIdx.x & 63;
  int i = (blockIdx.x * blockDim.x + threadIdx.x) >> 6;
  if (i >= n) return;
  int start = rowptr[i];
  int d = rowptr[i + 1] - start;
  float ad0 = adst[i];
  const float4* hf4 = (const float4*)hfeat;
  int g = lane >> 2;   // edge group 0..15
  int q = lane & 3;    // float4 channel slot
  const float2* sp = s_hw[wid];
  float4 acc = make_float4(0.f, 0.f, 0.f, 0.f);
  float sl = 0.f;

  if (d <= 64) {
    int sidx4 = 0;
    float e0 = -3.4e38f;
    if (lane < d) {
      int sidx = csr_src[start + lane];
      sidx4 = sidx << 2;
      e0 = leaky02(asrc[sidx] + ad0);
    }
    float m0 = e0;
#pragma unroll
    for (int off = 32; off >= 1; off >>= 1) m0 = fmaxf(m0, __shfl_xor(m0, off));
    float w0 = (lane < d) ? __expf(e0 - m0) : 0.f;
    sl = w0;
    s_hw[wid][lane] = make_float2(__int_as_float(sidx4), w0);
    gather3(sp, hf4, q, g, d, acc);
  } else {
    float m0 = -3.4e38f;
    for (int k = lane; k < d; k += 64) {
      int sidx = csr_src[start + k];
      m0 = fmaxf(m0, leaky02(asrc[sidx] + ad0));
    }
#pragma unroll
    for (int off = 32; off >= 1; off >>= 1) m0 = fmaxf(m0, __shfl_xor(m0, off));
    for (int base = 0; base < d; base += 64) {
      int k = base + lane;
      int sidx4 = 0;
      float w0 = 0.f;
      if (k < d) {
        int sidx = csr_src[start + k];
        sidx4 = sidx << 2;
        w0 = __expf(leaky02(asrc[sidx] + ad0) - m0);
        sl += w0;
      }
      s_hw[wid][lane] = make_float2(__int_as_float(sidx4), w0);
      int cnt = min(64, d - base);
      gather3(sp, hf4, q, g, cnt, acc);
    }
  }

#pragma unroll
  for (int off = 32; off >= 1; off >>= 1) sl += __shfl_xor(sl, off);
#pragma unroll
  for (int off = 4; off <= 32; off <<= 1) {
    acc.x += __shfl_xor(acc.x, off);
    acc.y += __shfl_xor(acc.y, off);
    acc.z += __shfl_xor(acc.z, off);
    acc.w += __shfl_xor(acc.w, off);
  }
  float z = 0.f;
  if (lane < 4) {
    float inv = 1.f / (sl + 1e-16f);
    float4 bv = ((const float4*)b3)[lane];
    float4 wv = ((const float4*)Wout)[lane];
    float4 o;
    o.x = eluf(acc.x * inv + bv.x);
    o.y = eluf(acc.y * inv + bv.y);
    o.z = eluf(acc.z * inv + bv.z);
    o.w = eluf(acc.w * inv + bv.w);
    ((float4*)(out + n))[(size_t)i * 4 + lane] = o;
    z = o.x * wv.x + o.y * wv.y + o.z * wv.z + o.w * wv.w;
  }
  z += __shfl_xor(z, 1);
  z += __shfl_xor(z, 2);
  if (lane == 0) out[i] = 1.f / (1.f + __expf(-(z + bout[0])));
}

// ====================== launch ======================

extern "C" void kernel_launch(void* const* d_in, const int* in_sizes, int n_in,
                              void* d_out, int out_size, void* d_ws, size_t ws_size,
                              hipStream_t stream) {
  const float* x    = (const float*)d_in[0];
  const int*   ei   = (const int*)d_in[1];
  const float* W1   = (const float*)d_in[2];
  const float* as1  = (const float*)d_in[3];
  const float* ad1  = (const float*)d_in[4];
  const float* b1   = (const float*)d_in[5];
  const float* W2   = (const float*)d_in[6];
  const float* as2  = (const float*)d_in[7];
  const float* ad2  = (const float*)d_in[8];
  const float* b2   = (const float*)d_in[9];
  const float* W3   = (const float*)d_in[10];
  const float* as3  = (const float*)d_in[11];
  const float* ad3  = (const float*)d_in[12];
  const float* b3   = (const float*)d_in[13];
  const float* Wout = (const float*)d_in[14];
  const float* bout = (const float*)d_in[15];
  float* out = (float*)d_out;

  const int n = in_sizes[0] / 3;
  const int E = in_sizes[1] / 2;
  const int Etot = E + n;
  const int* src = ei;
  const int* dst = ei + E;
  const int nbC = (Etot + CHUNK - 1) / CHUNK;
  const int NP = ((n - 1) >> PSH) + 1;   // n=100000 -> 98 partitions

  float* ws = (float*)d_ws;
  float* bufH = ws;                               // n*32
  float* bufX = bufH + (size_t)n * 32;            // n*32
  float* asrc = bufX + (size_t)n * 32;            // n*2
  float* adst = asrc + (size_t)n * 2;             // n*2
  int* rowptr  = (int*)(adst + (size_t)n * 2);    // n+1
  int* pbase   = rowptr + n + 1;                  // PMAX+1
  int* pcursor = pbase + PMAX + 1;                // PMAX
  int* pcount  = pcursor + PMAX;                  // PMAX (unused, layout kept)
  int* csr_src = pcount + PMAX;                   // Etot
  int* counts  = csr_src + Etot;                  // nbC*PMAX (~207 KB)
  unsigned* pstage = (unsigned*)ws;               // Etot (aliases bufH..; dead before transforms)

  const int nbN = (n + TPB - 1) / TPB;
  const int nbW = (n + 3) / 4;

  // ---- CSR build ----
  count_kernel<<<nbC, TPB, 0, stream>>>(dst, E, n, counts);
  pscan_kernel<<<1, 512, 0, stream>>>(counts, nbC, pbase, pcursor);
  scatter_kernel<<<nbC, TPB, 0, stream>>>(src, dst, E, n, counts, pcursor, pstage);
  build_csr_kernel<<<NP, 1024, 0, stream>>>(pstage, pbase, n, rowptr, csr_src);

  // ---- layer 1: in=3, out=32, H=2 ----
  transform_kernel<3, 32, 2><<<nbN, TPB, 0, stream>>>(x, W1, as1, ad1, bufH, asrc, adst, n);
  node_gat12<<<nbW, TPB, 0, stream>>>(rowptr, csr_src, asrc, adst, bufH, b1, bufX, n);

  // ---- layer 2: in=32, out=32, H=2 ----
  transform_kernel<32, 32, 2><<<nbN, TPB, 0, stream>>>(bufX, W2, as2, ad2, bufH, asrc, adst, n);
  node_gat12<<<nbW, TPB, 0, stream>>>(rowptr, csr_src, asrc, adst, bufH, b2, bufX, n);

  // ---- layer 3: in=32, out=16, H=1 ----
  transform_kernel<32, 16, 1><<<nbN, TPB, 0, stream>>>(bufX, W3, as3, ad3, bufH, asrc, adst, n);
  node_gat3<<<nbW, TPB, 0, stream>>>(rowptr, csr_src, asrc, adst, bufH, b3, Wout, bout, out, n);
}

// Round 3
// 386.841 us; speedup vs baseline: 1.0960x; 1.0382x over previous
//
#include <hip/hip_runtime.h>
#include <math.h>

#define TPB 256
#define PMAX 128       // max partitions
#define PSH 10         // partition = dst >> 10 (1024 nodes/partition; n <= 131072)
#define PW  1024       // nodes per partition
#define CHUNK 8192     // edges per block in count/scatter

__device__ __forceinline__ float leaky02(float x) { return x > 0.f ? x : 0.2f * x; }
__device__ __forceinline__ float eluf(float x) { return x > 0.f ? x : (__expf(x) - 1.f); }

// ====================== CSR build (radix-style: count -> scan -> scatter -> finalize) ======================

__global__ __launch_bounds__(256) void count_kernel(const int* __restrict__ dst, int E, int n,
                                                    int* __restrict__ counts) {
  __shared__ int lcnt[PMAX];
  int Etot = E + n;
  int c0 = blockIdx.x * CHUNK;
  if (c0 >= Etot) return;
  int c1 = min(c0 + CHUNK, Etot);
  for (int j = threadIdx.x; j < PMAX; j += TPB) lcnt[j] = 0;
  __syncthreads();
  for (int idx = c0 + threadIdx.x; idx < c1; idx += TPB) {
    int dd = (idx < E) ? dst[idx] : (idx - E);
    atomicAdd(&lcnt[dd >> PSH], 1);
  }
  __syncthreads();
  for (int j = threadIdx.x; j < PMAX; j += TPB)
    counts[blockIdx.x * PMAX + j] = lcnt[j];
}

// parallel partition scan: coalesced column-sum of counts[nbC][PMAX], then LDS scan.
__global__ __launch_bounds__(512) void pscan_kernel(const int* __restrict__ counts, int nbC,
                                                    int* __restrict__ pbase,
                                                    int* __restrict__ pcursor) {
  __shared__ int part[4][PMAX];
  __shared__ int ssum[PMAX];
  int t = threadIdx.x;
  int p = t & (PMAX - 1);
  int sub = t >> 7;
  int acc = 0;
#pragma unroll 4
  for (int b = sub; b < nbC; b += 4) acc += counts[b * PMAX + p];
  part[sub][p] = acc;
  __syncthreads();
  int own = 0;
  if (t < PMAX) {
    own = part[0][t] + part[1][t] + part[2][t] + part[3][t];
    ssum[t] = own;
  }
  __syncthreads();
  for (int off = 1; off < PMAX; off <<= 1) {
    int a = 0;
    if (t < PMAX && t >= off) a = ssum[t - off];
    __syncthreads();
    if (t < PMAX) ssum[t] += a;
    __syncthreads();
  }
  if (t < PMAX) {
    int incl = ssum[t];
    int excl = incl - own;
    pbase[t] = excl;
    pcursor[t] = excl;
    if (t == PMAX - 1) pbase[PMAX] = incl;
  }
}

__global__ __launch_bounds__(256) void scatter_kernel(const int* __restrict__ src,
                                                      const int* __restrict__ dst,
                                                      int E, int n,
                                                      const int* __restrict__ counts,
                                                      int* __restrict__ pcursor,
                                                      unsigned* __restrict__ pstage) {
  __shared__ int lbase[PMAX];
  __shared__ int lcnt[PMAX];
  int Etot = E + n;
  int c0 = blockIdx.x * CHUNK;
  if (c0 >= Etot) return;
  int c1 = min(c0 + CHUNK, Etot);
  for (int j = threadIdx.x; j < PMAX; j += TPB) {
    int c = counts[blockIdx.x * PMAX + j];
    lbase[j] = atomicAdd(&pcursor[j], c);
    lcnt[j] = 0;
  }
  __syncthreads();
  for (int idx = c0 + threadIdx.x; idx < c1; idx += TPB) {
    int ss, dd;
    if (idx < E) { ss = src[idx]; dd = dst[idx]; }
    else         { ss = dd = idx - E; }
    int p = dd >> PSH;
    int pos = lbase[p] + atomicAdd(&lcnt[p], 1);
    pstage[pos] = ((unsigned)ss << PSH) | (unsigned)(dd & (PW - 1));
  }
}

// One 1024-thread block per partition; shfl-based scan (4 barriers).
__global__ __launch_bounds__(1024) void build_csr_kernel(const unsigned* __restrict__ pstage,
                                                         const int* __restrict__ pbase,
                                                         int nvtx,
                                                         int* __restrict__ rowptr,
                                                         int* __restrict__ csr_src) {
  __shared__ int lhist[PW];
  __shared__ int lcur[PW];
  int t = threadIdx.x;
  int lane = t & 63;
  int wid = t >> 6;
  int p = blockIdx.x;
  int base = pbase[p];
  int end = pbase[p + 1];
  int nodebase = p << PSH;
  lhist[t] = 0;
  __syncthreads();
  for (int i = base + t; i < end; i += 1024)
    atomicAdd(&lhist[pstage[i] & (PW - 1)], 1);
  __syncthreads();
  int v = lhist[t];
  int x = v;
#pragma unroll
  for (int off = 1; off < 64; off <<= 1) {
    int u = __shfl_up(x, off);
    if (lane >= off) x += u;
  }
  if (lane == 63) lcur[wid] = x;       // wave sums in lcur[0..15]
  __syncthreads();
  if (t < 16) {
    int wsum = lcur[t];
    int y = wsum;
#pragma unroll
    for (int off = 1; off < 16; off <<= 1) {
      int u = __shfl_up(y, off);
      if (t >= off) y += u;
    }
    lcur[t] = y - wsum;                // exclusive wave offsets
  }
  __syncthreads();
  int acc = base + x + lcur[wid] - v;  // exclusive start position of node t
  __syncthreads();
  lcur[t] = acc;
  int node = nodebase + t;
  if (node < nvtx) rowptr[node] = acc;
  __syncthreads();
  for (int i = base + t; i < end; i += 1024) {
    unsigned w = pstage[i];
    int pos = atomicAdd(&lcur[w & (PW - 1)], 1);
    csr_src[pos] = (int)(w >> PSH);
  }
  if (p == (int)gridDim.x - 1 && t == 0) rowptr[nvtx] = end;
}

// ====================== node transform (h = x@W, attn logits) ======================

template<int IN, int OUT, int H>
__global__ void transform_kernel(const float* __restrict__ x, const float* __restrict__ W,
                                 const float* __restrict__ a_src, const float* __restrict__ a_dst,
                                 float* __restrict__ h, float* __restrict__ asrc,
                                 float* __restrict__ adst, int n) {
  __shared__ float sW[IN * OUT];
  __shared__ float sa[2 * OUT];
  for (int i = threadIdx.x; i < IN * OUT; i += blockDim.x) sW[i] = W[i];
  if (threadIdx.x < OUT) {
    sa[threadIdx.x] = a_src[threadIdx.x];
    sa[OUT + threadIdx.x] = a_dst[threadIdx.x];
  }
  __syncthreads();
  int i = blockIdx.x * blockDim.x + threadIdx.x;
  if (i >= n) return;
  float xv[IN];
#pragma unroll
  for (int k = 0; k < IN; k++) xv[k] = x[(size_t)i * IN + k];
  float hv[OUT];
#pragma unroll
  for (int j = 0; j < OUT; j++) {
    float acc = 0.f;
#pragma unroll
    for (int k = 0; k < IN; k++) acc += xv[k] * sW[k * OUT + j];
    hv[j] = acc;
    h[(size_t)i * OUT + j] = acc;
  }
#pragma unroll
  for (int hh = 0; hh < H; hh++) {
    float as = 0.f, ad = 0.f;
#pragma unroll
    for (int c = 0; c < 16; c++) {
      as += hv[hh * 16 + c] * sa[hh * 16 + c];
      ad += hv[hh * 16 + c] * sa[OUT + hh * 16 + c];
    }
    asrc[i * H + hh] = as;
    adst[i * H + hh] = ad;
  }
}

// ====================== per-node GAT aggregation (1 wave / dst node) ======================
// Branchless fixed-depth gather: s_e is fully zero-padded, so out-of-range reads
// contribute w=0 (feature load hits hfeat[0], L1-resident). 6 batched iterations
// (covers cnt<=48) + wave-uniform tail of 2 -> 6-8 loads in flight per lane.

__device__ __forceinline__ void gather12(const float2* __restrict__ sp,
                                         const float4* __restrict__ hf4,
                                         int q, int g, int cnt, float4& acc) {
  float2 p[6];
#pragma unroll
  for (int it = 0; it < 6; ++it) p[it] = sp[2 * (g + it * 8)];
  float4 h[6];
#pragma unroll
  for (int it = 0; it < 6; ++it) h[it] = hf4[__float_as_int(p[it].x) + q];
#pragma unroll
  for (int it = 0; it < 6; ++it) {
    acc.x += p[it].y * h[it].x; acc.y += p[it].y * h[it].y;
    acc.z += p[it].y * h[it].z; acc.w += p[it].y * h[it].w;
  }
  if (cnt > 48) {            // wave-uniform branch
    float2 pa = sp[2 * (g + 48)];
    float2 pb = sp[2 * (g + 56)];
    float4 ha = hf4[__float_as_int(pa.x) + q];
    float4 hb = hf4[__float_as_int(pb.x) + q];
    acc.x += pa.y * ha.x; acc.y += pa.y * ha.y; acc.z += pa.y * ha.z; acc.w += pa.y * ha.w;
    acc.x += pb.y * hb.x; acc.y += pb.y * hb.y; acc.z += pb.y * hb.z; acc.w += pb.y * hb.w;
  }
}

__global__ __launch_bounds__(256) void node_gat12(
    const int* __restrict__ rowptr,
    const int* __restrict__ csr_src,
    const float* __restrict__ asrc,  // [n*2]
    const float* __restrict__ adst,  // [n*2]
    const float* __restrict__ hfeat, // [n*32]
    const float* __restrict__ bias,  // [32]
    float* __restrict__ outb,        // [n*32]
    int n) {
  __shared__ float4 s_e[4][64];    // (sidx<<3, w0, sidx<<3, w1)
  int wid = threadIdx.x >> 6;
  int lane = threadIdx.x & 63;
  int i = (blockIdx.x * blockDim.x + threadIdx.x) >> 6;
  if (i >= n) return;
  int start = rowptr[i];
  int d = rowptr[i + 1] - start;
  float ad0 = adst[i * 2 + 0];
  float ad1 = adst[i * 2 + 1];
  const float4* hf4 = (const float4*)hfeat;
  int g = lane >> 3;   // edge group 0..7
  int q = lane & 7;    // float4 channel slot (q<4: head0, q>=4: head1)
  const float2* sp = (const float2*)(&s_e[wid][0]) + (q >> 2);  // head-selected base
  float4 acc = make_float4(0.f, 0.f, 0.f, 0.f);
  float sl0 = 0.f, sl1 = 0.f;

  if (d <= 64) {
    int sidx8 = 0;
    float e0 = -3.4e38f, e1 = -3.4e38f;
    if (lane < d) {
      int sidx = csr_src[start + lane];
      sidx8 = sidx << 3;
      float2 av = ((const float2*)asrc)[sidx];
      e0 = leaky02(av.x + ad0);
      e1 = leaky02(av.y + ad1);
    }
    float m0 = e0, m1 = e1;
#pragma unroll
    for (int off = 32; off >= 1; off >>= 1) {
      m0 = fmaxf(m0, __shfl_xor(m0, off));
      m1 = fmaxf(m1, __shfl_xor(m1, off));
    }
    float w0 = 0.f, w1 = 0.f;
    if (lane < d) { w0 = __expf(e0 - m0); w1 = __expf(e1 - m1); }
    sl0 = w0; sl1 = w1;
    s_e[wid][lane] = make_float4(__int_as_float(sidx8), w0, __int_as_float(sidx8), w1);
    // same-wave LDS write->read ordering (R4-verified)
    gather12(sp, hf4, q, g, d, acc);
  } else {
    float m0 = -3.4e38f, m1 = -3.4e38f;
    for (int k = lane; k < d; k += 64) {
      int sidx = csr_src[start + k];
      float2 av = ((const float2*)asrc)[sidx];
      m0 = fmaxf(m0, leaky02(av.x + ad0));
      m1 = fmaxf(m1, leaky02(av.y + ad1));
    }
#pragma unroll
    for (int off = 32; off >= 1; off >>= 1) {
      m0 = fmaxf(m0, __shfl_xor(m0, off));
      m1 = fmaxf(m1, __shfl_xor(m1, off));
    }
    for (int base = 0; base < d; base += 64) {
      int k = base + lane;
      int sidx8 = 0;
      float w0 = 0.f, w1 = 0.f;
      if (k < d) {
        int sidx = csr_src[start + k];
        sidx8 = sidx << 3;
        float2 av = ((const float2*)asrc)[sidx];
        w0 = __expf(leaky02(av.x + ad0) - m0);
        w1 = __expf(leaky02(av.y + ad1) - m1);
        sl0 += w0; sl1 += w1;
      }
      s_e[wid][lane] = make_float4(__int_as_float(sidx8), w0, __int_as_float(sidx8), w1);
      int cnt = min(64, d - base);
      gather12(sp, hf4, q, g, cnt, acc);
    }
  }

#pragma unroll
  for (int off = 32; off >= 1; off >>= 1) {
    sl0 += __shfl_xor(sl0, off);
    sl1 += __shfl_xor(sl1, off);
  }
#pragma unroll
  for (int off = 8; off <= 32; off <<= 1) {
    acc.x += __shfl_xor(acc.x, off);
    acc.y += __shfl_xor(acc.y, off);
    acc.z += __shfl_xor(acc.z, off);
    acc.w += __shfl_xor(acc.w, off);
  }
  if (lane < 8) {
    float inv = 1.f / (((lane >= 4) ? sl1 : sl0) + 1e-16f);
    float4 bv = ((const float4*)bias)[lane];
    float4 o;
    o.x = eluf(acc.x * inv + bv.x);
    o.y = eluf(acc.y * inv + bv.y);
    o.z = eluf(acc.z * inv + bv.z);
    o.w = eluf(acc.w * inv + bv.w);
    ((float4*)outb)[(size_t)i * 8 + lane] = o;
  }
}

// gat3: groups stride 16 -> fixed 4 iterations covers all cnt<=64 (jj max = 15+48 = 63).
__device__ __forceinline__ void gather3(const float2* __restrict__ sp,
                                        const float4* __restrict__ hf4,
                                        int q, int g, float4& acc) {
  float2 p[4];
#pragma unroll
  for (int it = 0; it < 4; ++it) p[it] = sp[g + it * 16];
  float4 h[4];
#pragma unroll
  for (int it = 0; it < 4; ++it) h[it] = hf4[__float_as_int(p[it].x) + q];
#pragma unroll
  for (int it = 0; it < 4; ++it) {
    acc.x += p[it].y * h[it].x; acc.y += p[it].y * h[it].y;
    acc.z += p[it].y * h[it].z; acc.w += p[it].y * h[it].w;
  }
}

__global__ __launch_bounds__(256) void node_gat3(
    const int* __restrict__ rowptr,
    const int* __restrict__ csr_src,
    const float* __restrict__ asrc,  // [n]
    const float* __restrict__ adst,  // [n]
    const float* __restrict__ hfeat, // [n*16]
    const float* __restrict__ b3,    // [16]
    const float* __restrict__ Wout,  // [16]
    const float* __restrict__ bout,  // [1]
    float* __restrict__ out,         // [n] sigmoid ++ [n*16] embeddings
    int n) {
  __shared__ float2 s_hw[4][64];   // (sidx<<2, w)
  int wid = threadIdx.x >> 6;
  int lane = threadIdx.x & 63;
  int i = (blockIdx.x * blockDim.x + threadIdx.x) >> 6;
  if (i >= n) return;
  int start = rowptr[i];
  int d = rowptr[i + 1] - start;
  float ad0 = adst[i];
  const float4* hf4 = (const float4*)hfeat;
  int g = lane >> 2;   // edge group 0..15
  int q = lane & 3;    // float4 channel slot
  const float2* sp = s_hw[wid];
  float4 acc = make_float4(0.f, 0.f, 0.f, 0.f);
  float sl = 0.f;

  if (d <= 64) {
    int sidx4 = 0;
    float e0 = -3.4e38f;
    if (lane < d) {
      int sidx = csr_src[start + lane];
      sidx4 = sidx << 2;
      e0 = leaky02(asrc[sidx] + ad0);
    }
    float m0 = e0;
#pragma unroll
    for (int off = 32; off >= 1; off >>= 1) m0 = fmaxf(m0, __shfl_xor(m0, off));
    float w0 = (lane < d) ? __expf(e0 - m0) : 0.f;
    sl = w0;
    s_hw[wid][lane] = make_float2(__int_as_float(sidx4), w0);
    gather3(sp, hf4, q, g, acc);
  } else {
    float m0 = -3.4e38f;
    for (int k = lane; k < d; k += 64) {
      int sidx = csr_src[start + k];
      m0 = fmaxf(m0, leaky02(asrc[sidx] + ad0));
    }
#pragma unroll
    for (int off = 32; off >= 1; off >>= 1) m0 = fmaxf(m0, __shfl_xor(m0, off));
    for (int base = 0; base < d; base += 64) {
      int k = base + lane;
      int sidx4 = 0;
      float w0 = 0.f;
      if (k < d) {
        int sidx = csr_src[start + k];
        sidx4 = sidx << 2;
        w0 = __expf(leaky02(asrc[sidx] + ad0) - m0);
        sl += w0;
      }
      s_hw[wid][lane] = make_float2(__int_as_float(sidx4), w0);
      gather3(sp, hf4, q, g, acc);
    }
  }

#pragma unroll
  for (int off = 32; off >= 1; off >>= 1) sl += __shfl_xor(sl, off);
#pragma unroll
  for (int off = 4; off <= 32; off <<= 1) {
    acc.x += __shfl_xor(acc.x, off);
    acc.y += __shfl_xor(acc.y, off);
    acc.z += __shfl_xor(acc.z, off);
    acc.w += __shfl_xor(acc.w, off);
  }
  float z = 0.f;
  if (lane < 4) {
    float inv = 1.f / (sl + 1e-16f);
    float4 bv = ((const float4*)b3)[lane];
    float4 wv = ((const float4*)Wout)[lane];
    float4 o;
    o.x = eluf(acc.x * inv + bv.x);
    o.y = eluf(acc.y * inv + bv.y);
    o.z = eluf(acc.z * inv + bv.z);
    o.w = eluf(acc.w * inv + bv.w);
    ((float4*)(out + n))[(size_t)i * 4 + lane] = o;
    z = o.x * wv.x + o.y * wv.y + o.z * wv.z + o.w * wv.w;
  }
  z += __shfl_xor(z, 1);
  z += __shfl_xor(z, 2);
  if (lane == 0) out[i] = 1.f / (1.f + __expf(-(z + bout[0])));
}

// ====================== launch ======================

extern "C" void kernel_launch(void* const* d_in, const int* in_sizes, int n_in,
                              void* d_out, int out_size, void* d_ws, size_t ws_size,
                              hipStream_t stream) {
  const float* x    = (const float*)d_in[0];
  const int*   ei   = (const int*)d_in[1];
  const float* W1   = (const float*)d_in[2];
  const float* as1  = (const float*)d_in[3];
  const float* ad1  = (const float*)d_in[4];
  const float* b1   = (const float*)d_in[5];
  const float* W2   = (const float*)d_in[6];
  const float* as2  = (const float*)d_in[7];
  const float* ad2  = (const float*)d_in[8];
  const float* b2   = (const float*)d_in[9];
  const float* W3   = (const float*)d_in[10];
  const float* as3  = (const float*)d_in[11];
  const float* ad3  = (const float*)d_in[12];
  const float* b3   = (const float*)d_in[13];
  const float* Wout = (const float*)d_in[14];
  const float* bout = (const float*)d_in[15];
  float* out = (float*)d_out;

  const int n = in_sizes[0] / 3;
  const int E = in_sizes[1] / 2;
  const int Etot = E + n;
  const int* src = ei;
  const int* dst = ei + E;
  const int nbC = (Etot + CHUNK - 1) / CHUNK;
  const int NP = ((n - 1) >> PSH) + 1;   // n=100000 -> 98 partitions

  float* ws = (float*)d_ws;
  float* bufH = ws;                               // n*32
  float* bufX = bufH + (size_t)n * 32;            // n*32
  float* asrc = bufX + (size_t)n * 32;            // n*2
  float* adst = asrc + (size_t)n * 2;             // n*2
  int* rowptr  = (int*)(adst + (size_t)n * 2);    // n+1
  int* pbase   = rowptr + n + 1;                  // PMAX+1
  int* pcursor = pbase + PMAX + 1;                // PMAX
  int* pcount  = pcursor + PMAX;                  // PMAX (unused, layout kept)
  int* csr_src = pcount + PMAX;                   // Etot
  int* counts  = csr_src + Etot;                  // nbC*PMAX (~207 KB)
  unsigned* pstage = (unsigned*)ws;               // Etot (aliases bufH..; dead before transforms)

  const int nbN = (n + TPB - 1) / TPB;
  const int nbW = (n + 3) / 4;

  // ---- CSR build ----
  count_kernel<<<nbC, TPB, 0, stream>>>(dst, E, n, counts);
  pscan_kernel<<<1, 512, 0, stream>>>(counts, nbC, pbase, pcursor);
  scatter_kernel<<<nbC, TPB, 0, stream>>>(src, dst, E, n, counts, pcursor, pstage);
  build_csr_kernel<<<NP, 1024, 0, stream>>>(pstage, pbase, n, rowptr, csr_src);

  // ---- layer 1: in=3, out=32, H=2 ----
  transform_kernel<3, 32, 2><<<nbN, TPB, 0, stream>>>(x, W1, as1, ad1, bufH, asrc, adst, n);
  node_gat12<<<nbW, TPB, 0, stream>>>(rowptr, csr_src, asrc, adst, bufH, b1, bufX, n);

  // ---- layer 2: in=32, out=32, H=2 ----
  transform_kernel<32, 32, 2><<<nbN, TPB, 0, stream>>>(bufX, W2, as2, ad2, bufH, asrc, adst, n);
  node_gat12<<<nbW, TPB, 0, stream>>>(rowptr, csr_src, asrc, adst, bufH, b2, bufX, n);

  // ---- layer 3: in=32, out=16, H=1 ----
  transform_kernel<32, 16, 1><<<nbN, TPB, 0, stream>>>(bufX, W3, as3, ad3, bufH, asrc, adst, n);
  node_gat3<<<nbW, TPB, 0, stream>>>(rowptr, csr_src, asrc, adst, bufH, b3, Wout, bout, out, n);
}

// Round 4
// 386.232 us; speedup vs baseline: 1.0978x; 1.0016x over previous
//
#include <hip/hip_runtime.h>
#include <math.h>

#define TPB 256
#define PMAX 128       // max partitions
#define PSH 10         // partition = dst >> 10 (1024 nodes/partition; n <= 131072)
#define PW  1024       // nodes per partition
#define CHUNK 8192     // edges per block in count/scatter

__device__ __forceinline__ float leaky02(float x) { return x > 0.f ? x : 0.2f * x; }
__device__ __forceinline__ float eluf(float x) { return x > 0.f ? x : (__expf(x) - 1.f); }

// ====================== CSR build (radix-style: count -> scan -> scatter -> finalize) ======================

__global__ __launch_bounds__(256) void count_kernel(const int* __restrict__ dst, int E, int n,
                                                    int* __restrict__ counts) {
  __shared__ int lcnt[PMAX];
  int Etot = E + n;
  int c0 = blockIdx.x * CHUNK;
  if (c0 >= Etot) return;
  int c1 = min(c0 + CHUNK, Etot);
  for (int j = threadIdx.x; j < PMAX; j += TPB) lcnt[j] = 0;
  __syncthreads();
  for (int idx = c0 + threadIdx.x; idx < c1; idx += TPB) {
    int dd = (idx < E) ? dst[idx] : (idx - E);
    atomicAdd(&lcnt[dd >> PSH], 1);
  }
  __syncthreads();
  for (int j = threadIdx.x; j < PMAX; j += TPB)
    counts[blockIdx.x * PMAX + j] = lcnt[j];
}

// parallel partition scan: coalesced column-sum of counts[nbC][PMAX], then LDS scan.
__global__ __launch_bounds__(512) void pscan_kernel(const int* __restrict__ counts, int nbC,
                                                    int* __restrict__ pbase,
                                                    int* __restrict__ pcursor) {
  __shared__ int part[4][PMAX];
  __shared__ int ssum[PMAX];
  int t = threadIdx.x;
  int p = t & (PMAX - 1);
  int sub = t >> 7;
  int acc = 0;
#pragma unroll 4
  for (int b = sub; b < nbC; b += 4) acc += counts[b * PMAX + p];
  part[sub][p] = acc;
  __syncthreads();
  int own = 0;
  if (t < PMAX) {
    own = part[0][t] + part[1][t] + part[2][t] + part[3][t];
    ssum[t] = own;
  }
  __syncthreads();
  for (int off = 1; off < PMAX; off <<= 1) {
    int a = 0;
    if (t < PMAX && t >= off) a = ssum[t - off];
    __syncthreads();
    if (t < PMAX) ssum[t] += a;
    __syncthreads();
  }
  if (t < PMAX) {
    int incl = ssum[t];
    int excl = incl - own;
    pbase[t] = excl;
    pcursor[t] = excl;
    if (t == PMAX - 1) pbase[PMAX] = incl;
  }
}

__global__ __launch_bounds__(256) void scatter_kernel(const int* __restrict__ src,
                                                      const int* __restrict__ dst,
                                                      int E, int n,
                                                      const int* __restrict__ counts,
                                                      int* __restrict__ pcursor,
                                                      unsigned* __restrict__ pstage) {
  __shared__ int lbase[PMAX];
  __shared__ int lcnt[PMAX];
  int Etot = E + n;
  int c0 = blockIdx.x * CHUNK;
  if (c0 >= Etot) return;
  int c1 = min(c0 + CHUNK, Etot);
  for (int j = threadIdx.x; j < PMAX; j += TPB) {
    int c = counts[blockIdx.x * PMAX + j];
    lbase[j] = atomicAdd(&pcursor[j], c);
    lcnt[j] = 0;
  }
  __syncthreads();
  for (int idx = c0 + threadIdx.x; idx < c1; idx += TPB) {
    int ss, dd;
    if (idx < E) { ss = src[idx]; dd = dst[idx]; }
    else         { ss = dd = idx - E; }
    int p = dd >> PSH;
    int pos = lbase[p] + atomicAdd(&lcnt[p], 1);
    pstage[pos] = ((unsigned)ss << PSH) | (unsigned)(dd & (PW - 1));
  }
}

// One 1024-thread block per partition; shfl-based scan (4 barriers).
__global__ __launch_bounds__(1024) void build_csr_kernel(const unsigned* __restrict__ pstage,
                                                         const int* __restrict__ pbase,
                                                         int nvtx,
                                                         int* __restrict__ rowptr,
                                                         int* __restrict__ csr_src) {
  __shared__ int lhist[PW];
  __shared__ int lcur[PW];
  int t = threadIdx.x;
  int lane = t & 63;
  int wid = t >> 6;
  int p = blockIdx.x;
  int base = pbase[p];
  int end = pbase[p + 1];
  int nodebase = p << PSH;
  lhist[t] = 0;
  __syncthreads();
  for (int i = base + t; i < end; i += 1024)
    atomicAdd(&lhist[pstage[i] & (PW - 1)], 1);
  __syncthreads();
  int v = lhist[t];
  int x = v;
#pragma unroll
  for (int off = 1; off < 64; off <<= 1) {
    int u = __shfl_up(x, off);
    if (lane >= off) x += u;
  }
  if (lane == 63) lcur[wid] = x;       // wave sums in lcur[0..15]
  __syncthreads();
  if (t < 16) {
    int wsum = lcur[t];
    int y = wsum;
#pragma unroll
    for (int off = 1; off < 16; off <<= 1) {
      int u = __shfl_up(y, off);
      if (t >= off) y += u;
    }
    lcur[t] = y - wsum;                // exclusive wave offsets
  }
  __syncthreads();
  int acc = base + x + lcur[wid] - v;  // exclusive start position of node t
  __syncthreads();
  lcur[t] = acc;
  int node = nodebase + t;
  if (node < nvtx) rowptr[node] = acc;
  __syncthreads();
  for (int i = base + t; i < end; i += 1024) {
    unsigned w = pstage[i];
    int pos = atomicAdd(&lcur[w & (PW - 1)], 1);
    csr_src[pos] = (int)(w >> PSH);
  }
  if (p == (int)gridDim.x - 1 && t == 0) rowptr[nvtx] = end;
}

// ====================== node transform (h = x@W, attn logits) ======================

template<int IN, int OUT, int H>
__global__ void transform_kernel(const float* __restrict__ x, const float* __restrict__ W,
                                 const float* __restrict__ a_src, const float* __restrict__ a_dst,
                                 float* __restrict__ h, float* __restrict__ asrc,
                                 float* __restrict__ adst, int n) {
  __shared__ float sW[IN * OUT];
  __shared__ float sa[2 * OUT];
  for (int i = threadIdx.x; i < IN * OUT; i += blockDim.x) sW[i] = W[i];
  if (threadIdx.x < OUT) {
    sa[threadIdx.x] = a_src[threadIdx.x];
    sa[OUT + threadIdx.x] = a_dst[threadIdx.x];
  }
  __syncthreads();
  int i = blockIdx.x * blockDim.x + threadIdx.x;
  if (i >= n) return;
  float xv[IN];
#pragma unroll
  for (int k = 0; k < IN; k++) xv[k] = x[(size_t)i * IN + k];
  float hv[OUT];
#pragma unroll
  for (int j = 0; j < OUT; j++) {
    float acc = 0.f;
#pragma unroll
    for (int k = 0; k < IN; k++) acc += xv[k] * sW[k * OUT + j];
    hv[j] = acc;
    h[(size_t)i * OUT + j] = acc;
  }
#pragma unroll
  for (int hh = 0; hh < H; hh++) {
    float as = 0.f, ad = 0.f;
#pragma unroll
    for (int c = 0; c < 16; c++) {
      as += hv[hh * 16 + c] * sa[hh * 16 + c];
      ad += hv[hh * 16 + c] * sa[OUT + hh * 16 + c];
    }
    asrc[i * H + hh] = as;
    adst[i * H + hh] = ad;
  }
}

// ====================== per-node GAT aggregation (1 wave / dst node) ======================
// Early-issue gather: indices are known BEFORE the softmax, so the feature
// loads are issued first and the shfl-max/exp/LDS-write chain runs while
// they are in flight. NIT tiered on wave-uniform d to cut wasted loads.
// __launch_bounds__(256,4) -> VGPR cap 128 so h[NIT] stays live.

template<int NIT>
__device__ __forceinline__ void gat12_small(
    int lane, int d, int start,
    const int* __restrict__ csr_src, const float2* __restrict__ asrc2,
    float ad0, float ad1,
    const float4* __restrict__ hf4, int q, int g,
    int* __restrict__ s_idx, float2* __restrict__ s_w,
    float4& acc, float& sl0, float& sl1) {
  int sidx = 0;
  float2 av = make_float2(0.f, 0.f);
  if (lane < d) {
    sidx = csr_src[start + lane];
    av = asrc2[sidx];
  }
  s_idx[lane] = sidx << 3;
  // early: read group indices, issue feature gathers (same-wave LDS w->r)
  int idx[NIT];
#pragma unroll
  for (int it = 0; it < NIT; ++it) idx[it] = s_idx[g + it * 8];
  float4 h[NIT];
#pragma unroll
  for (int it = 0; it < NIT; ++it) h[it] = hf4[idx[it] + q];
  // softmax overlaps with in-flight gathers
  float e0 = -3.4e38f, e1 = -3.4e38f;
  if (lane < d) { e0 = leaky02(av.x + ad0); e1 = leaky02(av.y + ad1); }
  float m0 = e0, m1 = e1;
#pragma unroll
  for (int off = 32; off >= 1; off >>= 1) {
    m0 = fmaxf(m0, __shfl_xor(m0, off));
    m1 = fmaxf(m1, __shfl_xor(m1, off));
  }
  float w0 = 0.f, w1 = 0.f;
  if (lane < d) { w0 = __expf(e0 - m0); w1 = __expf(e1 - m1); }
  sl0 = w0; sl1 = w1;
  s_w[lane] = make_float2(w0, w1);
#pragma unroll
  for (int it = 0; it < NIT; ++it) {
    float2 t = s_w[g + it * 8];
    float w = (q >= 4) ? t.y : t.x;
    acc.x += w * h[it].x; acc.y += w * h[it].y;
    acc.z += w * h[it].z; acc.w += w * h[it].w;
  }
}

__global__ __launch_bounds__(256, 4) void node_gat12(
    const int* __restrict__ rowptr,
    const int* __restrict__ csr_src,
    const float* __restrict__ asrc,  // [n*2]
    const float* __restrict__ adst,  // [n*2]
    const float* __restrict__ hfeat, // [n*32]
    const float* __restrict__ bias,  // [32]
    float* __restrict__ outb,        // [n*32]
    int n) {
  __shared__ int   s_idx[4][64];
  __shared__ float2 s_w[4][64];
  int wid = threadIdx.x >> 6;
  int lane = threadIdx.x & 63;
  int i = (blockIdx.x * blockDim.x + threadIdx.x) >> 6;
  if (i >= n) return;
  int start = rowptr[i];
  int d = rowptr[i + 1] - start;
  float ad0 = adst[i * 2 + 0];
  float ad1 = adst[i * 2 + 1];
  const float4* hf4 = (const float4*)hfeat;
  const float2* asrc2 = (const float2*)asrc;
  int g = lane >> 3;   // edge group 0..7
  int q = lane & 7;    // float4 channel slot (q<4: head0, q>=4: head1)
  float4 acc = make_float4(0.f, 0.f, 0.f, 0.f);
  float sl0 = 0.f, sl1 = 0.f;

  if (d <= 32) {
    gat12_small<4>(lane, d, start, csr_src, asrc2, ad0, ad1, hf4, q, g,
                   s_idx[wid], s_w[wid], acc, sl0, sl1);
  } else if (d <= 64) {
    gat12_small<8>(lane, d, start, csr_src, asrc2, ad0, ad1, hf4, q, g,
                   s_idx[wid], s_w[wid], acc, sl0, sl1);
  } else {
    float m0 = -3.4e38f, m1 = -3.4e38f;
    for (int k = lane; k < d; k += 64) {
      int sidx = csr_src[start + k];
      float2 av = asrc2[sidx];
      m0 = fmaxf(m0, leaky02(av.x + ad0));
      m1 = fmaxf(m1, leaky02(av.y + ad1));
    }
#pragma unroll
    for (int off = 32; off >= 1; off >>= 1) {
      m0 = fmaxf(m0, __shfl_xor(m0, off));
      m1 = fmaxf(m1, __shfl_xor(m1, off));
    }
    for (int base = 0; base < d; base += 64) {
      int k = base + lane;
      int sidx = 0;
      float w0 = 0.f, w1 = 0.f;
      if (k < d) {
        sidx = csr_src[start + k];
        float2 av = asrc2[sidx];
        w0 = __expf(leaky02(av.x + ad0) - m0);
        w1 = __expf(leaky02(av.y + ad1) - m1);
        sl0 += w0; sl1 += w1;
      }
      s_idx[wid][lane] = sidx << 3;     // all 64 lanes rewrite -> zero-pad valid
      s_w[wid][lane] = make_float2(w0, w1);
      int idx[8];
#pragma unroll
      for (int it = 0; it < 8; ++it) idx[it] = s_idx[wid][g + it * 8];
      float4 h[8];
#pragma unroll
      for (int it = 0; it < 8; ++it) h[it] = hf4[idx[it] + q];
#pragma unroll
      for (int it = 0; it < 8; ++it) {
        float2 t = s_w[wid][g + it * 8];
        float w = (q >= 4) ? t.y : t.x;
        acc.x += w * h[it].x; acc.y += w * h[it].y;
        acc.z += w * h[it].z; acc.w += w * h[it].w;
      }
    }
  }

#pragma unroll
  for (int off = 32; off >= 1; off >>= 1) {
    sl0 += __shfl_xor(sl0, off);
    sl1 += __shfl_xor(sl1, off);
  }
#pragma unroll
  for (int off = 8; off <= 32; off <<= 1) {
    acc.x += __shfl_xor(acc.x, off);
    acc.y += __shfl_xor(acc.y, off);
    acc.z += __shfl_xor(acc.z, off);
    acc.w += __shfl_xor(acc.w, off);
  }
  if (lane < 8) {
    float inv = 1.f / (((lane >= 4) ? sl1 : sl0) + 1e-16f);
    float4 bv = ((const float4*)bias)[lane];
    float4 o;
    o.x = eluf(acc.x * inv + bv.x);
    o.y = eluf(acc.y * inv + bv.y);
    o.z = eluf(acc.z * inv + bv.z);
    o.w = eluf(acc.w * inv + bv.w);
    ((float4*)outb)[(size_t)i * 8 + lane] = o;
  }
}

template<int NIT>
__device__ __forceinline__ void gat3_small(
    int lane, int d, int start,
    const int* __restrict__ csr_src, const float* __restrict__ asrc,
    float ad0,
    const float4* __restrict__ hf4, int q, int g,
    int* __restrict__ s_idx, float* __restrict__ s_w,
    float4& acc, float& sl) {
  int sidx = 0;
  float as = 0.f;
  if (lane < d) {
    sidx = csr_src[start + lane];
    as = asrc[sidx];
  }
  s_idx[lane] = sidx << 2;
  int idx[NIT];
#pragma unroll
  for (int it = 0; it < NIT; ++it) idx[it] = s_idx[g + it * 16];
  float4 h[NIT];
#pragma unroll
  for (int it = 0; it < NIT; ++it) h[it] = hf4[idx[it] + q];
  float e0 = -3.4e38f;
  if (lane < d) e0 = leaky02(as + ad0);
  float m0 = e0;
#pragma unroll
  for (int off = 32; off >= 1; off >>= 1) m0 = fmaxf(m0, __shfl_xor(m0, off));
  float w0 = (lane < d) ? __expf(e0 - m0) : 0.f;
  sl = w0;
  s_w[lane] = w0;
#pragma unroll
  for (int it = 0; it < NIT; ++it) {
    float w = s_w[g + it * 16];
    acc.x += w * h[it].x; acc.y += w * h[it].y;
    acc.z += w * h[it].z; acc.w += w * h[it].w;
  }
}

__global__ __launch_bounds__(256, 4) void node_gat3(
    const int* __restrict__ rowptr,
    const int* __restrict__ csr_src,
    const float* __restrict__ asrc,  // [n]
    const float* __restrict__ adst,  // [n]
    const float* __restrict__ hfeat, // [n*16]
    const float* __restrict__ b3,    // [16]
    const float* __restrict__ Wout,  // [16]
    const float* __restrict__ bout,  // [1]
    float* __restrict__ out,         // [n] sigmoid ++ [n*16] embeddings
    int n) {
  __shared__ int   s_idx[4][64];
  __shared__ float s_w[4][64];
  int wid = threadIdx.x >> 6;
  int lane = threadIdx.x & 63;
  int i = (blockIdx.x * blockDim.x + threadIdx.x) >> 6;
  if (i >= n) return;
  int start = rowptr[i];
  int d = rowptr[i + 1] - start;
  float ad0 = adst[i];
  const float4* hf4 = (const float4*)hfeat;
  int g = lane >> 2;   // edge group 0..15
  int q = lane & 3;    // float4 channel slot
  float4 acc = make_float4(0.f, 0.f, 0.f, 0.f);
  float sl = 0.f;

  if (d <= 32) {
    gat3_small<2>(lane, d, start, csr_src, asrc, ad0, hf4, q, g,
                  s_idx[wid], s_w[wid], acc, sl);
  } else if (d <= 64) {
    gat3_small<4>(lane, d, start, csr_src, asrc, ad0, hf4, q, g,
                  s_idx[wid], s_w[wid], acc, sl);
  } else {
    float m0 = -3.4e38f;
    for (int k = lane; k < d; k += 64) {
      int sidx = csr_src[start + k];
      m0 = fmaxf(m0, leaky02(asrc[sidx] + ad0));
    }
#pragma unroll
    for (int off = 32; off >= 1; off >>= 1) m0 = fmaxf(m0, __shfl_xor(m0, off));
    for (int base = 0; base < d; base += 64) {
      int k = base + lane;
      int sidx = 0;
      float w0 = 0.f;
      if (k < d) {
        sidx = csr_src[start + k];
        w0 = __expf(leaky02(asrc[sidx] + ad0) - m0);
        sl += w0;
      }
      s_idx[wid][lane] = sidx << 2;
      s_w[wid][lane] = w0;
      int idx[4];
#pragma unroll
      for (int it = 0; it < 4; ++it) idx[it] = s_idx[wid][g + it * 16];
      float4 h[4];
#pragma unroll
      for (int it = 0; it < 4; ++it) h[it] = hf4[idx[it] + q];
#pragma unroll
      for (int it = 0; it < 4; ++it) {
        float w = s_w[wid][g + it * 16];
        acc.x += w * h[it].x; acc.y += w * h[it].y;
        acc.z += w * h[it].z; acc.w += w * h[it].w;
      }
    }
  }

#pragma unroll
  for (int off = 32; off >= 1; off >>= 1) sl += __shfl_xor(sl, off);
#pragma unroll
  for (int off = 4; off <= 32; off <<= 1) {
    acc.x += __shfl_xor(acc.x, off);
    acc.y += __shfl_xor(acc.y, off);
    acc.z += __shfl_xor(acc.z, off);
    acc.w += __shfl_xor(acc.w, off);
  }
  float z = 0.f;
  if (lane < 4) {
    float inv = 1.f / (sl + 1e-16f);
    float4 bv = ((const float4*)b3)[lane];
    float4 wv = ((const float4*)Wout)[lane];
    float4 o;
    o.x = eluf(acc.x * inv + bv.x);
    o.y = eluf(acc.y * inv + bv.y);
    o.z = eluf(acc.z * inv + bv.z);
    o.w = eluf(acc.w * inv + bv.w);
    ((float4*)(out + n))[(size_t)i * 4 + lane] = o;
    z = o.x * wv.x + o.y * wv.y + o.z * wv.z + o.w * wv.w;
  }
  z += __shfl_xor(z, 1);
  z += __shfl_xor(z, 2);
  if (lane == 0) out[i] = 1.f / (1.f + __expf(-(z + bout[0])));
}

// ====================== launch ======================

extern "C" void kernel_launch(void* const* d_in, const int* in_sizes, int n_in,
                              void* d_out, int out_size, void* d_ws, size_t ws_size,
                              hipStream_t stream) {
  const float* x    = (const float*)d_in[0];
  const int*   ei   = (const int*)d_in[1];
  const float* W1   = (const float*)d_in[2];
  const float* as1  = (const float*)d_in[3];
  const float* ad1  = (const float*)d_in[4];
  const float* b1   = (const float*)d_in[5];
  const float* W2   = (const float*)d_in[6];
  const float* as2  = (const float*)d_in[7];
  const float* ad2  = (const float*)d_in[8];
  const float* b2   = (const float*)d_in[9];
  const float* W3   = (const float*)d_in[10];
  const float* as3  = (const float*)d_in[11];
  const float* ad3  = (const float*)d_in[12];
  const float* b3   = (const float*)d_in[13];
  const float* Wout = (const float*)d_in[14];
  const float* bout = (const float*)d_in[15];
  float* out = (float*)d_out;

  const int n = in_sizes[0] / 3;
  const int E = in_sizes[1] / 2;
  const int Etot = E + n;
  const int* src = ei;
  const int* dst = ei + E;
  const int nbC = (Etot + CHUNK - 1) / CHUNK;
  const int NP = ((n - 1) >> PSH) + 1;   // n=100000 -> 98 partitions

  float* ws = (float*)d_ws;
  float* bufH = ws;                               // n*32
  float* bufX = bufH + (size_t)n * 32;            // n*32
  float* asrc = bufX + (size_t)n * 32;            // n*2
  float* adst = asrc + (size_t)n * 2;             // n*2
  int* rowptr  = (int*)(adst + (size_t)n * 2);    // n+1
  int* pbase   = rowptr + n + 1;                  // PMAX+1
  int* pcursor = pbase + PMAX + 1;                // PMAX
  int* pcount  = pcursor + PMAX;                  // PMAX (unused, layout kept)
  int* csr_src = pcount + PMAX;                   // Etot
  int* counts  = csr_src + Etot;                  // nbC*PMAX (~207 KB)
  unsigned* pstage = (unsigned*)ws;               // Etot (aliases bufH..; dead before transforms)

  const int nbN = (n + TPB - 1) / TPB;
  const int nbW = (n + 3) / 4;

  // ---- CSR build ----
  count_kernel<<<nbC, TPB, 0, stream>>>(dst, E, n, counts);
  pscan_kernel<<<1, 512, 0, stream>>>(counts, nbC, pbase, pcursor);
  scatter_kernel<<<nbC, TPB, 0, stream>>>(src, dst, E, n, counts, pcursor, pstage);
  build_csr_kernel<<<NP, 1024, 0, stream>>>(pstage, pbase, n, rowptr, csr_src);

  // ---- layer 1: in=3, out=32, H=2 ----
  transform_kernel<3, 32, 2><<<nbN, TPB, 0, stream>>>(x, W1, as1, ad1, bufH, asrc, adst, n);
  node_gat12<<<nbW, TPB, 0, stream>>>(rowptr, csr_src, asrc, adst, bufH, b1, bufX, n);

  // ---- layer 2: in=32, out=32, H=2 ----
  transform_kernel<32, 32, 2><<<nbN, TPB, 0, stream>>>(bufX, W2, as2, ad2, bufH, asrc, adst, n);
  node_gat12<<<nbW, TPB, 0, stream>>>(rowptr, csr_src, asrc, adst, bufH, b2, bufX, n);

  // ---- layer 3: in=32, out=16, H=1 ----
  transform_kernel<32, 16, 1><<<nbN, TPB, 0, stream>>>(bufX, W3, as3, ad3, bufH, asrc, adst, n);
  node_gat3<<<nbW, TPB, 0, stream>>>(rowptr, csr_src, asrc, adst, bufH, b3, Wout, bout, out, n);
}

// Round 5
// 369.002 us; speedup vs baseline: 1.1490x; 1.0467x over previous
//
#include <hip/hip_runtime.h>
#include <hip/hip_fp16.h>
#include <math.h>

#define TPB 256
#define PMAX 128       // max partitions
#define PSH 10         // partition = dst >> 10 (1024 nodes/partition; n <= 131072)
#define PW  1024       // nodes per partition
#define CHUNK 8192     // edges per block in count/scatter

__device__ __forceinline__ float leaky02(float x) { return x > 0.f ? x : 0.2f * x; }
__device__ __forceinline__ float eluf(float x) { return x > 0.f ? x : (__expf(x) - 1.f); }

// ====================== CSR build (radix-style: count -> scan -> scatter -> finalize) ======================

__global__ __launch_bounds__(256) void count_kernel(const int* __restrict__ dst, int E, int n,
                                                    int* __restrict__ counts) {
  __shared__ int lcnt[PMAX];
  int Etot = E + n;
  int c0 = blockIdx.x * CHUNK;
  if (c0 >= Etot) return;
  int c1 = min(c0 + CHUNK, Etot);
  for (int j = threadIdx.x; j < PMAX; j += TPB) lcnt[j] = 0;
  __syncthreads();
  for (int idx = c0 + threadIdx.x; idx < c1; idx += TPB) {
    int dd = (idx < E) ? dst[idx] : (idx - E);
    atomicAdd(&lcnt[dd >> PSH], 1);
  }
  __syncthreads();
  for (int j = threadIdx.x; j < PMAX; j += TPB)
    counts[blockIdx.x * PMAX + j] = lcnt[j];
}

// parallel partition scan: coalesced column-sum of counts[nbC][PMAX], then LDS scan.
__global__ __launch_bounds__(512) void pscan_kernel(const int* __restrict__ counts, int nbC,
                                                    int* __restrict__ pbase,
                                                    int* __restrict__ pcursor) {
  __shared__ int part[4][PMAX];
  __shared__ int ssum[PMAX];
  int t = threadIdx.x;
  int p = t & (PMAX - 1);
  int sub = t >> 7;
  int acc = 0;
#pragma unroll 4
  for (int b = sub; b < nbC; b += 4) acc += counts[b * PMAX + p];
  part[sub][p] = acc;
  __syncthreads();
  int own = 0;
  if (t < PMAX) {
    own = part[0][t] + part[1][t] + part[2][t] + part[3][t];
    ssum[t] = own;
  }
  __syncthreads();
  for (int off = 1; off < PMAX; off <<= 1) {
    int a = 0;
    if (t < PMAX && t >= off) a = ssum[t - off];
    __syncthreads();
    if (t < PMAX) ssum[t] += a;
    __syncthreads();
  }
  if (t < PMAX) {
    int incl = ssum[t];
    int excl = incl - own;
    pbase[t] = excl;
    pcursor[t] = excl;
    if (t == PMAX - 1) pbase[PMAX] = incl;
  }
}

__global__ __launch_bounds__(256) void scatter_kernel(const int* __restrict__ src,
                                                      const int* __restrict__ dst,
                                                      int E, int n,
                                                      const int* __restrict__ counts,
                                                      int* __restrict__ pcursor,
                                                      unsigned* __restrict__ pstage) {
  __shared__ int lbase[PMAX];
  __shared__ int lcnt[PMAX];
  int Etot = E + n;
  int c0 = blockIdx.x * CHUNK;
  if (c0 >= Etot) return;
  int c1 = min(c0 + CHUNK, Etot);
  for (int j = threadIdx.x; j < PMAX; j += TPB) {
    int c = counts[blockIdx.x * PMAX + j];
    lbase[j] = atomicAdd(&pcursor[j], c);
    lcnt[j] = 0;
  }
  __syncthreads();
  for (int idx = c0 + threadIdx.x; idx < c1; idx += TPB) {
    int ss, dd;
    if (idx < E) { ss = src[idx]; dd = dst[idx]; }
    else         { ss = dd = idx - E; }
    int p = dd >> PSH;
    int pos = lbase[p] + atomicAdd(&lcnt[p], 1);
    pstage[pos] = ((unsigned)ss << PSH) | (unsigned)(dd & (PW - 1));
  }
}

// One 1024-thread block per partition; shfl-based scan (4 barriers).
__global__ __launch_bounds__(1024) void build_csr_kernel(const unsigned* __restrict__ pstage,
                                                         const int* __restrict__ pbase,
                                                         int nvtx,
                                                         int* __restrict__ rowptr,
                                                         int* __restrict__ csr_src) {
  __shared__ int lhist[PW];
  __shared__ int lcur[PW];
  int t = threadIdx.x;
  int lane = t & 63;
  int wid = t >> 6;
  int p = blockIdx.x;
  int base = pbase[p];
  int end = pbase[p + 1];
  int nodebase = p << PSH;
  lhist[t] = 0;
  __syncthreads();
  for (int i = base + t; i < end; i += 1024)
    atomicAdd(&lhist[pstage[i] & (PW - 1)], 1);
  __syncthreads();
  int v = lhist[t];
  int x = v;
#pragma unroll
  for (int off = 1; off < 64; off <<= 1) {
    int u = __shfl_up(x, off);
    if (lane >= off) x += u;
  }
  if (lane == 63) lcur[wid] = x;       // wave sums in lcur[0..15]
  __syncthreads();
  if (t < 16) {
    int wsum = lcur[t];
    int y = wsum;
#pragma unroll
    for (int off = 1; off < 16; off <<= 1) {
      int u = __shfl_up(y, off);
      if (t >= off) y += u;
    }
    lcur[t] = y - wsum;                // exclusive wave offsets
  }
  __syncthreads();
  int acc = base + x + lcur[wid] - v;  // exclusive start position of node t
  __syncthreads();
  lcur[t] = acc;
  int node = nodebase + t;
  if (node < nvtx) rowptr[node] = acc;
  __syncthreads();
  for (int i = base + t; i < end; i += 1024) {
    unsigned w = pstage[i];
    int pos = atomicAdd(&lcur[w & (PW - 1)], 1);
    csr_src[pos] = (int)(w >> PSH);
  }
  if (p == (int)gridDim.x - 1 && t == 0) rowptr[nvtx] = end;
}

// ====================== node transform (h = x@W fp32 -> stored fp16, attn logits fp32) ======================

template<int IN, int OUT, int H>
__global__ void transform_kernel(const float* __restrict__ x, const float* __restrict__ W,
                                 const float* __restrict__ a_src, const float* __restrict__ a_dst,
                                 __half* __restrict__ h, float* __restrict__ asrc,
                                 float* __restrict__ adst, int n) {
  __shared__ float sW[IN * OUT];
  __shared__ float sa[2 * OUT];
  for (int i = threadIdx.x; i < IN * OUT; i += blockDim.x) sW[i] = W[i];
  if (threadIdx.x < OUT) {
    sa[threadIdx.x] = a_src[threadIdx.x];
    sa[OUT + threadIdx.x] = a_dst[threadIdx.x];
  }
  __syncthreads();
  int i = blockIdx.x * blockDim.x + threadIdx.x;
  if (i >= n) return;
  float xv[IN];
#pragma unroll
  for (int k = 0; k < IN; k++) xv[k] = x[(size_t)i * IN + k];
  float hv[OUT];
#pragma unroll
  for (int j = 0; j < OUT; j++) {
    float acc = 0.f;
#pragma unroll
    for (int k = 0; k < IN; k++) acc += xv[k] * sW[k * OUT + j];
    hv[j] = acc;
  }
  // fp16 store of features (only quantization point in the pipeline)
#pragma unroll
  for (int j = 0; j < OUT; j += 2)
    ((__half2*)h)[((size_t)i * OUT + j) >> 1] = __floats2half2_rn(hv[j], hv[j + 1]);
  // logits from fp32 hv (no precision loss)
#pragma unroll
  for (int hh = 0; hh < H; hh++) {
    float as = 0.f, ad = 0.f;
#pragma unroll
    for (int c = 0; c < 16; c++) {
      as += hv[hh * 16 + c] * sa[hh * 16 + c];
      ad += hv[hh * 16 + c] * sa[OUT + hh * 16 + c];
    }
    asrc[i * H + hh] = as;
    adst[i * H + hh] = ad;
  }
}

// ====================== per-node GAT aggregation (1 wave / dst node) ======================
// fp16 feature gather (half4 = 8B per lane), fp32 accumulate. Packed (sidxOff, w0,
// sidxOff, w1) float4 LDS entry -> one ds_read_b64 per gather step. Uniform depth-8
// (gat12) / depth-4 (gat3): s_e fully zero-padded so over-depth reads add 0.

__global__ __launch_bounds__(256) void node_gat12(
    const int* __restrict__ rowptr,
    const int* __restrict__ csr_src,
    const float* __restrict__ asrc,  // [n*2] fp32
    const float* __restrict__ adst,  // [n*2] fp32
    const __half* __restrict__ hfeat,// [n*32] fp16
    const float* __restrict__ bias,  // [32]
    float* __restrict__ outb,        // [n*32] fp32
    int n) {
  __shared__ float4 s_e[4][64];    // (sidx<<3, w0, sidx<<3, w1)
  int wid = threadIdx.x >> 6;
  int lane = threadIdx.x & 63;
  int i = (blockIdx.x * blockDim.x + threadIdx.x) >> 6;
  if (i >= n) return;
  int start = rowptr[i];
  int d = rowptr[i + 1] - start;
  float ad0 = adst[i * 2 + 0];
  float ad1 = adst[i * 2 + 1];
  const uint2* hfp = (const uint2*)hfeat;   // half4 chunks; 8 per 32-ch row
  const float2* asrc2 = (const float2*)asrc;
  int g = lane >> 3;   // edge group 0..7
  int q = lane & 7;    // half4 chunk slot (q<4: head0 ch q*4.., q>=4: head1)
  const float2* sp = (const float2*)(&s_e[wid][0]) + (q >> 2);  // head-selected (idx,w) base
  float4 acc = make_float4(0.f, 0.f, 0.f, 0.f);
  float sl0 = 0.f, sl1 = 0.f;

  if (d <= 64) {
    int sidx8 = 0;
    float e0 = -3.4e38f, e1 = -3.4e38f;
    if (lane < d) {
      int sidx = csr_src[start + lane];
      sidx8 = sidx << 3;
      float2 av = asrc2[sidx];
      e0 = leaky02(av.x + ad0);
      e1 = leaky02(av.y + ad1);
    }
    float m0 = e0, m1 = e1;
#pragma unroll
    for (int off = 32; off >= 1; off >>= 1) {
      m0 = fmaxf(m0, __shfl_xor(m0, off));
      m1 = fmaxf(m1, __shfl_xor(m1, off));
    }
    float w0 = 0.f, w1 = 0.f;
    if (lane < d) { w0 = __expf(e0 - m0); w1 = __expf(e1 - m1); }
    sl0 = w0; sl1 = w1;
    s_e[wid][lane] = make_float4(__int_as_float(sidx8), w0, __int_as_float(sidx8), w1);
    // same-wave LDS write->read ordering (R4-verified); uniform depth-8 gather
    float2 p[8];
#pragma unroll
    for (int it = 0; it < 8; ++it) p[it] = sp[2 * (g + it * 8)];
    uint2 hv[8];
#pragma unroll
    for (int it = 0; it < 8; ++it) hv[it] = hfp[__float_as_int(p[it].x) + q];
#pragma unroll
    for (int it = 0; it < 8; ++it) {
      float2 fa = __half22float2(*(const __half2*)&hv[it].x);
      float2 fb = __half22float2(*(const __half2*)&hv[it].y);
      float w = p[it].y;
      acc.x += w * fa.x; acc.y += w * fa.y;
      acc.z += w * fb.x; acc.w += w * fb.y;
    }
  } else {
    float m0 = -3.4e38f, m1 = -3.4e38f;
    for (int k = lane; k < d; k += 64) {
      int sidx = csr_src[start + k];
      float2 av = asrc2[sidx];
      m0 = fmaxf(m0, leaky02(av.x + ad0));
      m1 = fmaxf(m1, leaky02(av.y + ad1));
    }
#pragma unroll
    for (int off = 32; off >= 1; off >>= 1) {
      m0 = fmaxf(m0, __shfl_xor(m0, off));
      m1 = fmaxf(m1, __shfl_xor(m1, off));
    }
    for (int base = 0; base < d; base += 64) {
      int k = base + lane;
      int sidx8 = 0;
      float w0 = 0.f, w1 = 0.f;
      if (k < d) {
        int sidx = csr_src[start + k];
        sidx8 = sidx << 3;
        float2 av = asrc2[sidx];
        w0 = __expf(leaky02(av.x + ad0) - m0);
        w1 = __expf(leaky02(av.y + ad1) - m1);
        sl0 += w0; sl1 += w1;
      }
      s_e[wid][lane] = make_float4(__int_as_float(sidx8), w0, __int_as_float(sidx8), w1);
      float2 p[8];
#pragma unroll
      for (int it = 0; it < 8; ++it) p[it] = sp[2 * (g + it * 8)];
      uint2 hv[8];
#pragma unroll
      for (int it = 0; it < 8; ++it) hv[it] = hfp[__float_as_int(p[it].x) + q];
#pragma unroll
      for (int it = 0; it < 8; ++it) {
        float2 fa = __half22float2(*(const __half2*)&hv[it].x);
        float2 fb = __half22float2(*(const __half2*)&hv[it].y);
        float w = p[it].y;
        acc.x += w * fa.x; acc.y += w * fa.y;
        acc.z += w * fb.x; acc.w += w * fb.y;
      }
    }
  }

#pragma unroll
  for (int off = 32; off >= 1; off >>= 1) {
    sl0 += __shfl_xor(sl0, off);
    sl1 += __shfl_xor(sl1, off);
  }
#pragma unroll
  for (int off = 8; off <= 32; off <<= 1) {
    acc.x += __shfl_xor(acc.x, off);
    acc.y += __shfl_xor(acc.y, off);
    acc.z += __shfl_xor(acc.z, off);
    acc.w += __shfl_xor(acc.w, off);
  }
  if (lane < 8) {
    float inv = 1.f / (((lane >= 4) ? sl1 : sl0) + 1e-16f);
    float4 bv = ((const float4*)bias)[lane];
    float4 o;
    o.x = eluf(acc.x * inv + bv.x);
    o.y = eluf(acc.y * inv + bv.y);
    o.z = eluf(acc.z * inv + bv.z);
    o.w = eluf(acc.w * inv + bv.w);
    ((float4*)outb)[(size_t)i * 8 + lane] = o;
  }
}

__global__ __launch_bounds__(256) void node_gat3(
    const int* __restrict__ rowptr,
    const int* __restrict__ csr_src,
    const float* __restrict__ asrc,  // [n] fp32
    const float* __restrict__ adst,  // [n] fp32
    const __half* __restrict__ hfeat,// [n*16] fp16
    const float* __restrict__ b3,    // [16]
    const float* __restrict__ Wout,  // [16]
    const float* __restrict__ bout,  // [1]
    float* __restrict__ out,         // [n] sigmoid ++ [n*16] embeddings (fp32)
    int n) {
  __shared__ float2 s_hw[4][64];   // (sidx<<2, w)
  int wid = threadIdx.x >> 6;
  int lane = threadIdx.x & 63;
  int i = (blockIdx.x * blockDim.x + threadIdx.x) >> 6;
  if (i >= n) return;
  int start = rowptr[i];
  int d = rowptr[i + 1] - start;
  float ad0 = adst[i];
  const uint2* hfp = (const uint2*)hfeat;   // half4 chunks; 4 per 16-ch row
  int g = lane >> 2;   // edge group 0..15
  int q = lane & 3;    // half4 chunk slot
  const float2* sp = s_hw[wid];
  float4 acc = make_float4(0.f, 0.f, 0.f, 0.f);
  float sl = 0.f;

  if (d <= 64) {
    int sidx4 = 0;
    float e0 = -3.4e38f;
    if (lane < d) {
      int sidx = csr_src[start + lane];
      sidx4 = sidx << 2;
      e0 = leaky02(asrc[sidx] + ad0);
    }
    float m0 = e0;
#pragma unroll
    for (int off = 32; off >= 1; off >>= 1) m0 = fmaxf(m0, __shfl_xor(m0, off));
    float w0 = (lane < d) ? __expf(e0 - m0) : 0.f;
    sl = w0;
    s_hw[wid][lane] = make_float2(__int_as_float(sidx4), w0);
    float2 p[4];
#pragma unroll
    for (int it = 0; it < 4; ++it) p[it] = sp[g + it * 16];
    uint2 hv[4];
#pragma unroll
    for (int it = 0; it < 4; ++it) hv[it] = hfp[__float_as_int(p[it].x) + q];
#pragma unroll
    for (int it = 0; it < 4; ++it) {
      float2 fa = __half22float2(*(const __half2*)&hv[it].x);
      float2 fb = __half22float2(*(const __half2*)&hv[it].y);
      float w = p[it].y;
      acc.x += w * fa.x; acc.y += w * fa.y;
      acc.z += w * fb.x; acc.w += w * fb.y;
    }
  } else {
    float m0 = -3.4e38f;
    for (int k = lane; k < d; k += 64) {
      int sidx = csr_src[start + k];
      m0 = fmaxf(m0, leaky02(asrc[sidx] + ad0));
    }
#pragma unroll
    for (int off = 32; off >= 1; off >>= 1) m0 = fmaxf(m0, __shfl_xor(m0, off));
    for (int base = 0; base < d; base += 64) {
      int k = base + lane;
      int sidx4 = 0;
      float w0 = 0.f;
      if (k < d) {
        int sidx = csr_src[start + k];
        sidx4 = sidx << 2;
        w0 = __expf(leaky02(asrc[sidx] + ad0) - m0);
        sl += w0;
      }
      s_hw[wid][lane] = make_float2(__int_as_float(sidx4), w0);
      float2 p[4];
#pragma unroll
      for (int it = 0; it < 4; ++it) p[it] = sp[g + it * 16];
      uint2 hv[4];
#pragma unroll
      for (int it = 0; it < 4; ++it) hv[it] = hfp[__float_as_int(p[it].x) + q];
#pragma unroll
      for (int it = 0; it < 4; ++it) {
        float2 fa = __half22float2(*(const __half2*)&hv[it].x);
        float2 fb = __half22float2(*(const __half2*)&hv[it].y);
        float w = p[it].y;
        acc.x += w * fa.x; acc.y += w * fa.y;
        acc.z += w * fb.x; acc.w += w * fb.y;
      }
    }
  }

#pragma unroll
  for (int off = 32; off >= 1; off >>= 1) sl += __shfl_xor(sl, off);
#pragma unroll
  for (int off = 4; off <= 32; off <<= 1) {
    acc.x += __shfl_xor(acc.x, off);
    acc.y += __shfl_xor(acc.y, off);
    acc.z += __shfl_xor(acc.z, off);
    acc.w += __shfl_xor(acc.w, off);
  }
  float z = 0.f;
  if (lane < 4) {
    float inv = 1.f / (sl + 1e-16f);
    float4 bv = ((const float4*)b3)[lane];
    float4 wv = ((const float4*)Wout)[lane];
    float4 o;
    o.x = eluf(acc.x * inv + bv.x);
    o.y = eluf(acc.y * inv + bv.y);
    o.z = eluf(acc.z * inv + bv.z);
    o.w = eluf(acc.w * inv + bv.w);
    ((float4*)(out + n))[(size_t)i * 4 + lane] = o;
    z = o.x * wv.x + o.y * wv.y + o.z * wv.z + o.w * wv.w;
  }
  z += __shfl_xor(z, 1);
  z += __shfl_xor(z, 2);
  if (lane == 0) out[i] = 1.f / (1.f + __expf(-(z + bout[0])));
}

// ====================== launch ======================

extern "C" void kernel_launch(void* const* d_in, const int* in_sizes, int n_in,
                              void* d_out, int out_size, void* d_ws, size_t ws_size,
                              hipStream_t stream) {
  const float* x    = (const float*)d_in[0];
  const int*   ei   = (const int*)d_in[1];
  const float* W1   = (const float*)d_in[2];
  const float* as1  = (const float*)d_in[3];
  const float* ad1  = (const float*)d_in[4];
  const float* b1   = (const float*)d_in[5];
  const float* W2   = (const float*)d_in[6];
  const float* as2  = (const float*)d_in[7];
  const float* ad2  = (const float*)d_in[8];
  const float* b2   = (const float*)d_in[9];
  const float* W3   = (const float*)d_in[10];
  const float* as3  = (const float*)d_in[11];
  const float* ad3  = (const float*)d_in[12];
  const float* b3   = (const float*)d_in[13];
  const float* Wout = (const float*)d_in[14];
  const float* bout = (const float*)d_in[15];
  float* out = (float*)d_out;

  const int n = in_sizes[0] / 3;
  const int E = in_sizes[1] / 2;
  const int Etot = E + n;
  const int* src = ei;
  const int* dst = ei + E;
  const int nbC = (Etot + CHUNK - 1) / CHUNK;
  const int NP = ((n - 1) >> PSH) + 1;   // n=100000 -> 98 partitions

  float* ws = (float*)d_ws;
  float* bufH = ws;                               // n*32 floats (used as n*32 halves for h)
  float* bufX = bufH + (size_t)n * 32;            // n*32 fp32 (gat output / next-layer x)
  float* asrc = bufX + (size_t)n * 32;            // n*2
  float* adst = asrc + (size_t)n * 2;             // n*2
  int* rowptr  = (int*)(adst + (size_t)n * 2);    // n+1
  int* pbase   = rowptr + n + 1;                  // PMAX+1
  int* pcursor = pbase + PMAX + 1;                // PMAX
  int* pcount  = pcursor + PMAX;                  // PMAX (unused, layout kept)
  int* csr_src = pcount + PMAX;                   // Etot
  int* counts  = csr_src + Etot;                  // nbC*PMAX (~207 KB)
  unsigned* pstage = (unsigned*)ws;               // Etot (aliases bufH..; dead before transforms)
  __half* hH = (__half*)bufH;

  const int nbN = (n + TPB - 1) / TPB;
  const int nbW = (n + 3) / 4;

  // ---- CSR build ----
  count_kernel<<<nbC, TPB, 0, stream>>>(dst, E, n, counts);
  pscan_kernel<<<1, 512, 0, stream>>>(counts, nbC, pbase, pcursor);
  scatter_kernel<<<nbC, TPB, 0, stream>>>(src, dst, E, n, counts, pcursor, pstage);
  build_csr_kernel<<<NP, 1024, 0, stream>>>(pstage, pbase, n, rowptr, csr_src);

  // ---- layer 1: in=3, out=32, H=2 ----
  transform_kernel<3, 32, 2><<<nbN, TPB, 0, stream>>>(x, W1, as1, ad1, hH, asrc, adst, n);
  node_gat12<<<nbW, TPB, 0, stream>>>(rowptr, csr_src, asrc, adst, hH, b1, bufX, n);

  // ---- layer 2: in=32, out=32, H=2 ----
  transform_kernel<32, 32, 2><<<nbN, TPB, 0, stream>>>(bufX, W2, as2, ad2, hH, asrc, adst, n);
  node_gat12<<<nbW, TPB, 0, stream>>>(rowptr, csr_src, asrc, adst, hH, b2, bufX, n);

  // ---- layer 3: in=32, out=16, H=1 ----
  transform_kernel<32, 16, 1><<<nbN, TPB, 0, stream>>>(bufX, W3, as3, ad3, hH, asrc, adst, n);
  node_gat3<<<nbW, TPB, 0, stream>>>(rowptr, csr_src, asrc, adst, hH, b3, Wout, bout, out, n);
}